// Round 1
// baseline (386.186 us; speedup 1.0000x reference)
//
#include <hip/hip_runtime.h>
#include <hip/hip_bf16.h>

typedef unsigned short u16;
typedef unsigned int u32;
using short8 = __attribute__((ext_vector_type(8))) short;
using f32x4  = __attribute__((ext_vector_type(4))) float;

__device__ __forceinline__ u16 f2bf(float f) {
    __hip_bfloat16 h = __float2bfloat16(f);
    union { __hip_bfloat16 h; u16 u; } cv; cv.h = h; return cv.u;
}

__device__ __forceinline__ void gload_lds16(const void* g, void* l) {
    __builtin_amdgcn_global_load_lds(
        (const __attribute__((address_space(1))) u32*)g,
        (__attribute__((address_space(3))) u32*)l, 16, 0, 0);
}

// ---------------- transpose + fp32->bf16 convert: W[K][N] -> Wt[N][K] ----------------
__global__ __launch_bounds__(256) void transpose_w(const float* __restrict__ W,
                                                   u16* __restrict__ Wt, int K, int N) {
    __shared__ float tile[32][33];
    int n0 = blockIdx.x * 32, k0 = blockIdx.y * 32;
    int tx = threadIdx.x & 31, ty = threadIdx.x >> 5;
    for (int i = 0; i < 4; i++) {
        int k = ty + i * 8;
        tile[k][tx] = W[(long)(k0 + k) * N + n0 + tx];
    }
    __syncthreads();
    for (int i = 0; i < 4; i++) {
        int n = ty + i * 8;
        Wt[(long)(n0 + n) * K + k0 + tx] = f2bf(tile[tx][n]);
    }
}

// ---------------- LayerNorm fp32 -> bf16 ----------------
__global__ __launch_bounds__(256) void ln_kernel(const float* __restrict__ x,
                                                 const float* __restrict__ gain,
                                                 const float* __restrict__ beta,
                                                 u16* __restrict__ out) {
    int row = blockIdx.x;
    const float* xr = x + (long)row * 768;
    int tid = threadIdx.x;
    float v[3];
    float s = 0.f, s2 = 0.f;
    for (int j = 0; j < 3; j++) {
        v[j] = xr[tid + 256 * j];
        s += v[j]; s2 += v[j] * v[j];
    }
    for (int off = 32; off; off >>= 1) {
        s  += __shfl_down(s, off);
        s2 += __shfl_down(s2, off);
    }
    __shared__ float ws[8];
    int lane = tid & 63, w = tid >> 6;
    if (lane == 0) { ws[w] = s; ws[4 + w] = s2; }
    __syncthreads();
    s  = ws[0] + ws[1] + ws[2] + ws[3];
    s2 = ws[4] + ws[5] + ws[6] + ws[7];
    float mu  = s * (1.f / 768.f);
    float var = s2 * (1.f / 768.f) - mu * mu;
    float rs  = rsqrtf(var + 1e-5f);
    for (int j = 0; j < 3; j++) {
        int c = tid + 256 * j;
        out[(long)row * 768 + c] = f2bf((v[j] - mu) * rs * gain[c] + beta[c]);
    }
}

// ---------------- bf16 GEMM: C = A[MxK] * Bt[NxK]^T + bias (+epilogue) ----------------
// EPI 0: bias -> bf16 out; EPI 1: bias + residual -> fp32 out; EPI 2: bias + gelu -> bf16 out
template <int EPI>
__global__ __launch_bounds__(256) void gemm_bf16(const u16* __restrict__ A,
                                                 const u16* __restrict__ Bt,
                                                 const float* __restrict__ bias,
                                                 const float* __restrict__ res,
                                                 void* __restrict__ Cout,
                                                 int M, int N, int K) {
    constexpr int BK = 32;
    __shared__ alignas(16) u16 As[128 * BK];
    __shared__ alignas(16) u16 Bs[128 * BK];
    int tN = blockIdx.x * 128, tM = blockIdx.y * 128;
    int tid = threadIdx.x;
    int wid = tid >> 6, lane = tid & 63;
    int wm = wid >> 1, wn = wid & 1;
    int g = lane >> 4, r = lane & 15;

    f32x4 acc[4][4] = {};

    const u16* Ag = A + (long)(tM + wid * 32 + (lane >> 2)) * K + (lane & 3) * 8;
    const u16* Bg = Bt + (long)(tN + wid * 32 + (lane >> 2)) * K + (lane & 3) * 8;
    u16* Asw = As + wid * 32 * BK;
    u16* Bsw = Bs + wid * 32 * BK;

    for (int k0 = 0; k0 < K; k0 += BK) {
        __syncthreads();
        gload_lds16(Ag + k0, Asw);
        gload_lds16(Ag + (long)16 * K + k0, Asw + 512);
        gload_lds16(Bg + k0, Bsw);
        gload_lds16(Bg + (long)16 * K + k0, Bsw + 512);
        __syncthreads();
        short8 af[4], bf[4];
        #pragma unroll
        for (int mi = 0; mi < 4; mi++)
            af[mi] = *(const short8*)(As + (wm * 64 + mi * 16 + r) * BK + g * 8);
        #pragma unroll
        for (int ni = 0; ni < 4; ni++)
            bf[ni] = *(const short8*)(Bs + (wn * 64 + ni * 16 + r) * BK + g * 8);
        #pragma unroll
        for (int mi = 0; mi < 4; mi++)
            #pragma unroll
            for (int ni = 0; ni < 4; ni++)
                acc[mi][ni] = __builtin_amdgcn_mfma_f32_16x16x32_bf16(af[mi], bf[ni], acc[mi][ni], 0, 0, 0);
    }

    #pragma unroll
    for (int mi = 0; mi < 4; mi++) {
        #pragma unroll
        for (int ni = 0; ni < 4; ni++) {
            int col = tN + wn * 64 + ni * 16 + r;
            float bv = bias[col];
            #pragma unroll
            for (int reg = 0; reg < 4; reg++) {
                int row = tM + wm * 64 + mi * 16 + g * 4 + reg;
                float v = acc[mi][ni][reg] + bv;
                if (EPI == 1) {
                    v += res[(long)row * N + col];
                    ((float*)Cout)[(long)row * N + col] = v;
                } else if (EPI == 2) {
                    v = 0.5f * v * (1.f + erff(v * 0.70710678118f));
                    ((u16*)Cout)[(long)row * N + col] = f2bf(v);
                } else {
                    ((u16*)Cout)[(long)row * N + col] = f2bf(v);
                }
            }
        }
    }
}

// ---------------- flash attention, causal; qkv bf16 [B][S][3*768]; O bf16 [B*S][768] --------
__global__ __launch_bounds__(64) void attn_kernel(const u16* __restrict__ qkv,
                                                  u16* __restrict__ O) {
    __shared__ alignas(16) u16 Kt[32 * 64];
    __shared__ alignas(16) u16 Vt[32 * 64];
    __shared__ alignas(16) u16 Pt[16 * 32];
    int qt = blockIdx.x;
    int bh = blockIdx.y;
    int b = bh / 12, h = bh % 12;
    int lane = threadIdx.x;
    int g = lane >> 4, r = lane & 15;
    const long rs = 2304;
    const u16* base = qkv + (long)b * 2048 * 2304;
    const u16* Qb = base + h * 64;
    const u16* Kb = base + 768 + h * 64;
    const u16* Vb = base + 1536 + h * 64;

    short8 qf[2];
    {
        const u16* qrow = Qb + (long)(qt * 16 + r) * rs;
        qf[0] = *(const short8*)(qrow + 8 * g);
        qf[1] = *(const short8*)(qrow + 32 + 8 * g);
    }
    f32x4 oacc[4] = {};
    float mrow[4], lrow[4];
    #pragma unroll
    for (int i = 0; i < 4; i++) { mrow[i] = -1e30f; lrow[i] = 0.f; }

    int ktmax = (qt * 16 + 16 + 31) / 32;
    for (int kt = 0; kt < ktmax; ++kt) {
        __syncthreads();
        {
            const u16* kg = Kb + (long)(kt * 32 + (lane >> 3)) * rs + (lane & 7) * 8;
            const u16* vg = Vb + (long)(kt * 32 + (lane >> 3)) * rs + (lane & 7) * 8;
            gload_lds16(kg, Kt);
            gload_lds16(kg + 8 * rs, Kt + 512);
            gload_lds16(kg + 16 * rs, Kt + 1024);
            gload_lds16(kg + 24 * rs, Kt + 1536);
            gload_lds16(vg, Vt);
            gload_lds16(vg + 8 * rs, Vt + 512);
            gload_lds16(vg + 16 * rs, Vt + 1024);
            gload_lds16(vg + 24 * rs, Vt + 1536);
        }
        __syncthreads();

        f32x4 sc[2] = {};
        #pragma unroll
        for (int nt = 0; nt < 2; ++nt)
            #pragma unroll
            for (int kh = 0; kh < 2; ++kh) {
                short8 bk = *(const short8*)(Kt + (nt * 16 + r) * 64 + kh * 32 + 8 * g);
                sc[nt] = __builtin_amdgcn_mfma_f32_16x16x32_bf16(qf[kh], bk, sc[nt], 0, 0, 0);
            }

        bool last = (kt == ktmax - 1);
        float tmax[4];
        #pragma unroll
        for (int reg = 0; reg < 4; reg++) tmax[reg] = -1e30f;
        #pragma unroll
        for (int nt = 0; nt < 2; nt++) {
            int colg = kt * 32 + nt * 16 + r;
            #pragma unroll
            for (int reg = 0; reg < 4; reg++) {
                float sv = sc[nt][reg] * 0.125f;
                int rowg = qt * 16 + g * 4 + reg;
                if (last && colg > rowg) sv = -1e30f;
                sc[nt][reg] = sv;
                tmax[reg] = fmaxf(tmax[reg], sv);
            }
        }
        #pragma unroll
        for (int off = 1; off < 16; off <<= 1)
            #pragma unroll
            for (int reg = 0; reg < 4; reg++)
                tmax[reg] = fmaxf(tmax[reg], __shfl_xor(tmax[reg], off));

        float alpha[4], psum[4];
        #pragma unroll
        for (int reg = 0; reg < 4; reg++) {
            float mnew = fmaxf(mrow[reg], tmax[reg]);
            alpha[reg] = __expf(mrow[reg] - mnew);
            mrow[reg] = mnew;
            psum[reg] = 0.f;
        }
        float pv[2][4];
        #pragma unroll
        for (int nt = 0; nt < 2; nt++)
            #pragma unroll
            for (int reg = 0; reg < 4; reg++) {
                float p = __expf(sc[nt][reg] - mrow[reg]);
                pv[nt][reg] = p;
                psum[reg] += p;
            }
        #pragma unroll
        for (int off = 1; off < 16; off <<= 1)
            #pragma unroll
            for (int reg = 0; reg < 4; reg++)
                psum[reg] += __shfl_xor(psum[reg], off);
        #pragma unroll
        for (int reg = 0; reg < 4; reg++)
            lrow[reg] = lrow[reg] * alpha[reg] + psum[reg];

        #pragma unroll
        for (int nt = 0; nt < 2; nt++)
            #pragma unroll
            for (int reg = 0; reg < 4; reg++)
                Pt[(g * 4 + reg) * 32 + nt * 16 + r] = f2bf(pv[nt][reg]);
        #pragma unroll
        for (int nt = 0; nt < 4; nt++)
            #pragma unroll
            for (int reg = 0; reg < 4; reg++)
                oacc[nt][reg] *= alpha[reg];
        __syncthreads();

        short8 pf = *(const short8*)(Pt + r * 32 + 8 * g);
        #pragma unroll
        for (int nt = 0; nt < 4; nt++) {
            short8 vf;
            #pragma unroll
            for (int j = 0; j < 8; j++)
                vf[j] = (short)Vt[(8 * g + j) * 64 + nt * 16 + r];
            oacc[nt] = __builtin_amdgcn_mfma_f32_16x16x32_bf16(pf, vf, oacc[nt], 0, 0, 0);
        }
    }

    #pragma unroll
    for (int nt = 0; nt < 4; nt++)
        #pragma unroll
        for (int reg = 0; reg < 4; reg++) {
            int q = qt * 16 + g * 4 + reg;
            int d = nt * 16 + r;
            O[(long)(b * 2048 + q) * 768 + h * 64 + d] = f2bf(oacc[nt][reg] / lrow[reg]);
        }
}

extern "C" void kernel_launch(void* const* d_in, const int* in_sizes, int n_in,
                              void* d_out, int out_size, void* d_ws, size_t ws_size,
                              hipStream_t stream) {
    const float* x     = (const float*)d_in[0];
    const float* ln1_g = (const float*)d_in[1];
    const float* ln1_b = (const float*)d_in[2];
    const float* ln2_g = (const float*)d_in[3];
    const float* ln2_b = (const float*)d_in[4];
    const float* w_qkv = (const float*)d_in[5];
    const float* b_qkv = (const float*)d_in[6];
    const float* w_out = (const float*)d_in[7];
    const float* b_out = (const float*)d_in[8];
    const float* w_fc1 = (const float*)d_in[9];
    const float* b_fc1 = (const float*)d_in[10];
    const float* w_fc2 = (const float*)d_in[11];
    const float* b_fc2 = (const float*)d_in[12];

    char* ws = (char*)d_ws;
    size_t off = 0;
    auto alloc = [&](size_t bytes) { void* p = ws + off; off += (bytes + 255) & ~255ULL; return p; };
    u16* h1    = (u16*)alloc(4096UL * 768 * 2);
    u16* WqkvT = (u16*)alloc(2304UL * 768 * 2);
    u16* WoutT = (u16*)alloc(768UL * 768 * 2);
    u16* Wfc1T = (u16*)alloc(3072UL * 768 * 2);
    u16* Wfc2T = (u16*)alloc(768UL * 3072 * 2);
    u16* qkvb  = (u16*)alloc(4096UL * 2304 * 2);
    u16* Ob    = (u16*)alloc(4096UL * 768 * 2);
    float* x2  = (float*)alloc(4096UL * 768 * 4);
    u16* h2    = (u16*)alloc(4096UL * 768 * 2);
    u16* gbuf  = (u16*)alloc(4096UL * 3072 * 2);

    transpose_w<<<dim3(2304 / 32, 768 / 32), 256, 0, stream>>>(w_qkv, WqkvT, 768, 2304);
    transpose_w<<<dim3(768 / 32, 768 / 32), 256, 0, stream>>>(w_out, WoutT, 768, 768);
    transpose_w<<<dim3(3072 / 32, 768 / 32), 256, 0, stream>>>(w_fc1, Wfc1T, 768, 3072);
    transpose_w<<<dim3(768 / 32, 3072 / 32), 256, 0, stream>>>(w_fc2, Wfc2T, 3072, 768);

    ln_kernel<<<4096, 256, 0, stream>>>(x, ln1_g, ln1_b, h1);
    gemm_bf16<0><<<dim3(2304 / 128, 4096 / 128), 256, 0, stream>>>(h1, WqkvT, b_qkv, nullptr, qkvb, 4096, 2304, 768);
    attn_kernel<<<dim3(128, 24), 64, 0, stream>>>(qkvb, Ob);
    gemm_bf16<1><<<dim3(768 / 128, 4096 / 128), 256, 0, stream>>>(Ob, WoutT, b_out, x, x2, 4096, 768, 768);
    ln_kernel<<<4096, 256, 0, stream>>>(x2, ln2_g, ln2_b, h2);
    gemm_bf16<2><<<dim3(3072 / 128, 4096 / 128), 256, 0, stream>>>(h2, Wfc1T, b_fc1, nullptr, gbuf, 4096, 3072, 768);
    gemm_bf16<1><<<dim3(768 / 128, 4096 / 128), 256, 0, stream>>>(gbuf, Wfc2T, b_fc2, x2, (float*)d_out, 4096, 768, 3072);
}

// Round 2
// 306.226 us; speedup vs baseline: 1.2611x; 1.2611x over previous
//
#include <hip/hip_runtime.h>
#include <hip/hip_bf16.h>

typedef unsigned short u16;
typedef unsigned int u32;
using short8 = __attribute__((ext_vector_type(8))) short;
using f32x4  = __attribute__((ext_vector_type(4))) float;

__device__ __forceinline__ u16 f2bf(float f) {
    __hip_bfloat16 h = __float2bfloat16(f);
    union { __hip_bfloat16 h; u16 u; } cv; cv.h = h; return cv.u;
}

__device__ __forceinline__ void gload_lds16(const void* g, void* l) {
    __builtin_amdgcn_global_load_lds(
        (const __attribute__((address_space(1))) u32*)g,
        (__attribute__((address_space(3))) u32*)l, 16, 0, 0);
}

// ---------------- transpose + fp32->bf16 convert: W[K][N] -> Wt[N][K] ----------------
__global__ __launch_bounds__(256) void transpose_w(const float* __restrict__ W,
                                                   u16* __restrict__ Wt, int K, int N) {
    __shared__ float tile[32][33];
    int n0 = blockIdx.x * 32, k0 = blockIdx.y * 32;
    int tx = threadIdx.x & 31, ty = threadIdx.x >> 5;
    for (int i = 0; i < 4; i++) {
        int k = ty + i * 8;
        tile[k][tx] = W[(long)(k0 + k) * N + n0 + tx];
    }
    __syncthreads();
    for (int i = 0; i < 4; i++) {
        int n = ty + i * 8;
        Wt[(long)(n0 + n) * K + k0 + tx] = f2bf(tile[tx][n]);
    }
}

// ---------------- V transpose: qkv[B][S][2304] (V slice) -> Vt[B*H][64][2048] ------------
__global__ __launch_bounds__(256) void transpose_v(const u16* __restrict__ qkv,
                                                   u16* __restrict__ Vt) {
    __shared__ u16 tile[64][72];
    int s0 = blockIdx.x * 64;
    int bh = blockIdx.y;
    int b = bh / 12, h = bh % 12;
    int tid = threadIdx.x;
    const u16* src = qkv + (long)b * 2048 * 2304 + 1536 + h * 64;
    #pragma unroll
    for (int j = 0; j < 2; ++j) {
        int c = tid + j * 256;
        int srow = c >> 3, ch = c & 7;
        *(short8*)&tile[srow][ch * 8] = *(const short8*)(src + (long)(s0 + srow) * 2304 + ch * 8);
    }
    __syncthreads();
    u16* dst = Vt + (long)bh * 64 * 2048 + s0;
    #pragma unroll
    for (int j = 0; j < 2; ++j) {
        int c = tid + j * 256;
        int d = c >> 3, ch = c & 7;
        short8 v;
        #pragma unroll
        for (int e = 0; e < 8; ++e) v[e] = (short)tile[ch * 8 + e][d];
        *(short8*)(dst + (long)d * 2048 + ch * 8) = v;
    }
}

// ---------------- LayerNorm fp32 -> bf16 ----------------
__global__ __launch_bounds__(256) void ln_kernel(const float* __restrict__ x,
                                                 const float* __restrict__ gain,
                                                 const float* __restrict__ beta,
                                                 u16* __restrict__ out) {
    int row = blockIdx.x;
    const float* xr = x + (long)row * 768;
    int tid = threadIdx.x;
    float v[3];
    float s = 0.f, s2 = 0.f;
    for (int j = 0; j < 3; j++) {
        v[j] = xr[tid + 256 * j];
        s += v[j]; s2 += v[j] * v[j];
    }
    for (int off = 32; off; off >>= 1) {
        s  += __shfl_down(s, off);
        s2 += __shfl_down(s2, off);
    }
    __shared__ float ws[8];
    int lane = tid & 63, w = tid >> 6;
    if (lane == 0) { ws[w] = s; ws[4 + w] = s2; }
    __syncthreads();
    s  = ws[0] + ws[1] + ws[2] + ws[3];
    s2 = ws[4] + ws[5] + ws[6] + ws[7];
    float mu  = s * (1.f / 768.f);
    float var = s2 * (1.f / 768.f) - mu * mu;
    float rs  = rsqrtf(var + 1e-5f);
    for (int j = 0; j < 3; j++) {
        int c = tid + 256 * j;
        out[(long)row * 768 + c] = f2bf((v[j] - mu) * rs * gain[c] + beta[c]);
    }
}

// ---------------- bf16 GEMM: C = A[MxK] * Bt[NxK]^T + bias (+epilogue) ----------------
template <int EPI>
__global__ __launch_bounds__(256) void gemm_bf16(const u16* __restrict__ A,
                                                 const u16* __restrict__ Bt,
                                                 const float* __restrict__ bias,
                                                 const float* __restrict__ res,
                                                 void* __restrict__ Cout,
                                                 int M, int N, int K) {
    constexpr int BK = 32;
    __shared__ alignas(16) u16 As[128 * BK];
    __shared__ alignas(16) u16 Bs[128 * BK];
    int tN = blockIdx.x * 128, tM = blockIdx.y * 128;
    int tid = threadIdx.x;
    int wid = tid >> 6, lane = tid & 63;
    int wm = wid >> 1, wn = wid & 1;
    int g = lane >> 4, r = lane & 15;

    f32x4 acc[4][4] = {};

    const u16* Ag = A + (long)(tM + wid * 32 + (lane >> 2)) * K + (lane & 3) * 8;
    const u16* Bg = Bt + (long)(tN + wid * 32 + (lane >> 2)) * K + (lane & 3) * 8;
    u16* Asw = As + wid * 32 * BK;
    u16* Bsw = Bs + wid * 32 * BK;

    for (int k0 = 0; k0 < K; k0 += BK) {
        __syncthreads();
        gload_lds16(Ag + k0, Asw);
        gload_lds16(Ag + (long)16 * K + k0, Asw + 512);
        gload_lds16(Bg + k0, Bsw);
        gload_lds16(Bg + (long)16 * K + k0, Bsw + 512);
        __syncthreads();
        short8 af[4], bf[4];
        #pragma unroll
        for (int mi = 0; mi < 4; mi++)
            af[mi] = *(const short8*)(As + (wm * 64 + mi * 16 + r) * BK + g * 8);
        #pragma unroll
        for (int ni = 0; ni < 4; ni++)
            bf[ni] = *(const short8*)(Bs + (wn * 64 + ni * 16 + r) * BK + g * 8);
        #pragma unroll
        for (int mi = 0; mi < 4; mi++)
            #pragma unroll
            for (int ni = 0; ni < 4; ni++)
                acc[mi][ni] = __builtin_amdgcn_mfma_f32_16x16x32_bf16(af[mi], bf[ni], acc[mi][ni], 0, 0, 0);
    }

    #pragma unroll
    for (int mi = 0; mi < 4; mi++) {
        #pragma unroll
        for (int ni = 0; ni < 4; ni++) {
            int col = tN + wn * 64 + ni * 16 + r;
            float bv = bias[col];
            #pragma unroll
            for (int reg = 0; reg < 4; reg++) {
                int row = tM + wm * 64 + mi * 16 + g * 4 + reg;
                float v = acc[mi][ni][reg] + bv;
                if (EPI == 1) {
                    v += res[(long)row * N + col];
                    ((float*)Cout)[(long)row * N + col] = v;
                } else if (EPI == 2) {
                    v = 0.5f * v * (1.f + erff(v * 0.70710678118f));
                    ((u16*)Cout)[(long)row * N + col] = f2bf(v);
                } else {
                    ((u16*)Cout)[(long)row * N + col] = f2bf(v);
                }
            }
        }
    }
}

// ---------------- flash attention, causal, 4 waves x 16 q-rows, KVBLK=64 ----------------
// qkv bf16 [B][S][2304]; Vt bf16 [B*H][64][2048]; O bf16 [B*S][768]
__global__ __launch_bounds__(256) void attn_kernel(const u16* __restrict__ qkv,
                                                   const u16* __restrict__ Vt,
                                                   u16* __restrict__ O) {
    __shared__ alignas(16) u16 Ks[64 * 64];
    __shared__ alignas(16) u16 Vs[64 * 64];
    __shared__ alignas(16) u16 Ps[4 * 16 * 64];
    int qi = (int)gridDim.x - 1 - (int)blockIdx.x;   // heavy (long-loop) blocks dispatch first
    int bh = blockIdx.y;
    int b = bh / 12, h = bh % 12;
    int tid = threadIdx.x;
    int w = tid >> 6, lane = tid & 63;
    int g = lane >> 4, r = lane & 15;
    int qt0 = qi * 64;
    const u16* base = qkv + (long)b * 2048 * 2304;
    const u16* Qb = base + h * 64;
    const u16* Kb = base + 768 + h * 64;
    const u16* Vtb = Vt + (long)bh * 64 * 2048;

    short8 qf[2];
    {
        const u16* qrow = Qb + (long)(qt0 + w * 16 + r) * 2304;
        qf[0] = *(const short8*)(qrow + 8 * g);
        qf[1] = *(const short8*)(qrow + 32 + 8 * g);
    }
    f32x4 oacc[4] = {};
    float mrow[4], lrow[4];
    #pragma unroll
    for (int i = 0; i < 4; i++) { mrow[i] = -1e30f; lrow[i] = 0.f; }
    const float SC = 0.125f * 1.44269504f;   // fold log2(e): use exp2

    int ktmax = qi + 1;
    for (int kt = 0; kt < ktmax; ++kt) {
        int kv0 = kt * 64;
        __syncthreads();
        // stage K[kv0..+64)[0..64) and Vt[0..64)[kv0..+64), XOR-swizzled via source perm
        #pragma unroll
        for (int j = 0; j < 2; ++j) {
            int c = w * 128 + j * 64 + lane;
            int row = c >> 3;
            int slot = (c & 7) ^ (row & 7);
            gload_lds16(Kb + (long)(kv0 + row) * 2304 + slot * 8, Ks + (w * 128 + j * 64) * 8);
            gload_lds16(Vtb + (long)row * 2048 + kv0 + slot * 8, Vs + (w * 128 + j * 64) * 8);
        }
        __syncthreads();

        // QK^T: 4 col-tiles x (K=64 in 2 chunks)
        f32x4 sc[4] = {};
        #pragma unroll
        for (int nt = 0; nt < 4; ++nt) {
            #pragma unroll
            for (int kh = 0; kh < 2; ++kh) {
                int row = nt * 16 + r;
                short8 bk = *(const short8*)(Ks + row * 64 + ((kh * 32 + g * 8) ^ ((r & 7) << 3)));
                sc[nt] = __builtin_amdgcn_mfma_f32_16x16x32_bf16(qf[kh], bk, sc[nt], 0, 0, 0);
            }
        }

        bool last = (kt == ktmax - 1);
        float tmax[4];
        #pragma unroll
        for (int reg = 0; reg < 4; reg++) tmax[reg] = -1e30f;
        #pragma unroll
        for (int nt = 0; nt < 4; nt++) {
            #pragma unroll
            for (int reg = 0; reg < 4; reg++) {
                float sv = sc[nt][reg] * SC;
                if (last && (nt * 16 + r) > (w * 16 + g * 4 + reg)) sv = -1e30f;
                sc[nt][reg] = sv;
                tmax[reg] = fmaxf(tmax[reg], sv);
            }
        }
        #pragma unroll
        for (int off = 1; off < 16; off <<= 1)
            #pragma unroll
            for (int reg = 0; reg < 4; reg++)
                tmax[reg] = fmaxf(tmax[reg], __shfl_xor(tmax[reg], off));

        float alpha[4], psum[4];
        #pragma unroll
        for (int reg = 0; reg < 4; reg++) {
            float mnew = fmaxf(mrow[reg], tmax[reg]);
            alpha[reg] = exp2f(mrow[reg] - mnew);
            mrow[reg] = mnew;
            psum[reg] = 0.f;
        }
        float pv[4][4];
        #pragma unroll
        for (int nt = 0; nt < 4; nt++) {
            #pragma unroll
            for (int reg = 0; reg < 4; reg++) {
                float p = exp2f(sc[nt][reg] - mrow[reg]);
                pv[nt][reg] = p;
                psum[reg] += p;
            }
        }
        #pragma unroll
        for (int off = 1; off < 16; off <<= 1)
            #pragma unroll
            for (int reg = 0; reg < 4; reg++)
                psum[reg] += __shfl_xor(psum[reg], off);
        #pragma unroll
        for (int reg = 0; reg < 4; reg++)
            lrow[reg] = lrow[reg] * alpha[reg] + psum[reg];

        // P -> LDS (per-wave region, XOR-swizzled), then PV
        u16* Pw = Ps + w * 16 * 64;
        #pragma unroll
        for (int nt = 0; nt < 4; nt++) {
            #pragma unroll
            for (int reg = 0; reg < 4; reg++) {
                int row = g * 4 + reg;
                Pw[row * 64 + ((nt * 16 + r) ^ ((row & 7) << 3))] = f2bf(pv[nt][reg]);
            }
        }
        #pragma unroll
        for (int dt = 0; dt < 4; dt++)
            #pragma unroll
            for (int reg = 0; reg < 4; reg++)
                oacc[dt][reg] *= alpha[reg];

        short8 pf[2];
        pf[0] = *(const short8*)(Pw + r * 64 + ((g * 8) ^ ((r & 7) << 3)));
        pf[1] = *(const short8*)(Pw + r * 64 + ((32 + g * 8) ^ ((r & 7) << 3)));
        #pragma unroll
        for (int dt = 0; dt < 4; dt++) {
            #pragma unroll
            for (int kc = 0; kc < 2; kc++) {
                int row = dt * 16 + r;
                short8 vf = *(const short8*)(Vs + row * 64 + ((kc * 32 + g * 8) ^ ((r & 7) << 3)));
                oacc[dt] = __builtin_amdgcn_mfma_f32_16x16x32_bf16(pf[kc], vf, oacc[dt], 0, 0, 0);
            }
        }
    }

    #pragma unroll
    for (int dt = 0; dt < 4; dt++) {
        #pragma unroll
        for (int reg = 0; reg < 4; reg++) {
            int q = qt0 + w * 16 + g * 4 + reg;
            int d = dt * 16 + r;
            O[(long)(b * 2048 + q) * 768 + h * 64 + d] = f2bf(oacc[dt][reg] / lrow[reg]);
        }
    }
}

extern "C" void kernel_launch(void* const* d_in, const int* in_sizes, int n_in,
                              void* d_out, int out_size, void* d_ws, size_t ws_size,
                              hipStream_t stream) {
    const float* x     = (const float*)d_in[0];
    const float* ln1_g = (const float*)d_in[1];
    const float* ln1_b = (const float*)d_in[2];
    const float* ln2_g = (const float*)d_in[3];
    const float* ln2_b = (const float*)d_in[4];
    const float* w_qkv = (const float*)d_in[5];
    const float* b_qkv = (const float*)d_in[6];
    const float* w_out = (const float*)d_in[7];
    const float* b_out = (const float*)d_in[8];
    const float* w_fc1 = (const float*)d_in[9];
    const float* b_fc1 = (const float*)d_in[10];
    const float* w_fc2 = (const float*)d_in[11];
    const float* b_fc2 = (const float*)d_in[12];

    char* ws = (char*)d_ws;
    size_t off = 0;
    auto alloc = [&](size_t bytes) { void* p = ws + off; off += (bytes + 255) & ~255ULL; return p; };
    u16* h1    = (u16*)alloc(4096UL * 768 * 2);
    u16* WqkvT = (u16*)alloc(2304UL * 768 * 2);
    u16* WoutT = (u16*)alloc(768UL * 768 * 2);
    u16* Wfc1T = (u16*)alloc(3072UL * 768 * 2);
    u16* Wfc2T = (u16*)alloc(768UL * 3072 * 2);
    u16* qkvb  = (u16*)alloc(4096UL * 2304 * 2);
    u16* Vtb   = (u16*)alloc(24UL * 64 * 2048 * 2);
    u16* Ob    = (u16*)alloc(4096UL * 768 * 2);
    float* x2  = (float*)alloc(4096UL * 768 * 4);
    u16* h2    = (u16*)alloc(4096UL * 768 * 2);
    u16* gbuf  = (u16*)alloc(4096UL * 3072 * 2);

    transpose_w<<<dim3(2304 / 32, 768 / 32), 256, 0, stream>>>(w_qkv, WqkvT, 768, 2304);
    transpose_w<<<dim3(768 / 32, 768 / 32), 256, 0, stream>>>(w_out, WoutT, 768, 768);
    transpose_w<<<dim3(3072 / 32, 768 / 32), 256, 0, stream>>>(w_fc1, Wfc1T, 768, 3072);
    transpose_w<<<dim3(768 / 32, 3072 / 32), 256, 0, stream>>>(w_fc2, Wfc2T, 3072, 768);

    ln_kernel<<<4096, 256, 0, stream>>>(x, ln1_g, ln1_b, h1);
    gemm_bf16<0><<<dim3(2304 / 128, 4096 / 128), 256, 0, stream>>>(h1, WqkvT, b_qkv, nullptr, qkvb, 4096, 2304, 768);
    transpose_v<<<dim3(32, 24), 256, 0, stream>>>(qkvb, Vtb);
    attn_kernel<<<dim3(32, 24), 256, 0, stream>>>(qkvb, Vtb, Ob);
    gemm_bf16<1><<<dim3(768 / 128, 4096 / 128), 256, 0, stream>>>(Ob, WoutT, b_out, x, x2, 4096, 768, 768);
    ln_kernel<<<4096, 256, 0, stream>>>(x2, ln2_g, ln2_b, h2);
    gemm_bf16<2><<<dim3(3072 / 128, 4096 / 128), 256, 0, stream>>>(h2, Wfc1T, b_fc1, nullptr, gbuf, 4096, 3072, 768);
    gemm_bf16<1><<<dim3(768 / 128, 4096 / 128), 256, 0, stream>>>(gbuf, Wfc2T, b_fc2, x2, (float*)d_out, 4096, 768, 3072);
}

// Round 3
// 304.707 us; speedup vs baseline: 1.2674x; 1.0050x over previous
//
#include <hip/hip_runtime.h>
#include <hip/hip_bf16.h>

typedef unsigned short u16;
typedef unsigned int u32;
using short8 = __attribute__((ext_vector_type(8))) short;
using f32x4  = __attribute__((ext_vector_type(4))) float;

__device__ __forceinline__ u16 f2bf(float f) {
    __hip_bfloat16 h = __float2bfloat16(f);
    union { __hip_bfloat16 h; u16 u; } cv; cv.h = h; return cv.u;
}

__device__ __forceinline__ void gload_lds16(const void* g, void* l) {
    __builtin_amdgcn_global_load_lds(
        (const __attribute__((address_space(1))) u32*)g,
        (__attribute__((address_space(3))) u32*)l, 16, 0, 0);
}

// ---------------- transpose + fp32->bf16 convert: W[K][N] -> Wt[N][K] ----------------
__global__ __launch_bounds__(256) void transpose_w(const float* __restrict__ W,
                                                   u16* __restrict__ Wt, int K, int N) {
    __shared__ float tile[32][33];
    int n0 = blockIdx.x * 32, k0 = blockIdx.y * 32;
    int tx = threadIdx.x & 31, ty = threadIdx.x >> 5;
    for (int i = 0; i < 4; i++) {
        int k = ty + i * 8;
        tile[k][tx] = W[(long)(k0 + k) * N + n0 + tx];
    }
    __syncthreads();
    for (int i = 0; i < 4; i++) {
        int n = ty + i * 8;
        Wt[(long)(n0 + n) * K + k0 + tx] = f2bf(tile[tx][n]);
    }
}

// ---------------- V transpose: qkv[B][S][2304] (V slice) -> Vt[B*H][64][2048] ------------
__global__ __launch_bounds__(256) void transpose_v(const u16* __restrict__ qkv,
                                                   u16* __restrict__ Vt) {
    __shared__ u16 tile[64][72];
    int s0 = blockIdx.x * 64;
    int bh = blockIdx.y;
    int b = bh / 12, h = bh % 12;
    int tid = threadIdx.x;
    const u16* src = qkv + (long)b * 2048 * 2304 + 1536 + h * 64;
    #pragma unroll
    for (int j = 0; j < 2; ++j) {
        int c = tid + j * 256;
        int srow = c >> 3, ch = c & 7;
        *(short8*)&tile[srow][ch * 8] = *(const short8*)(src + (long)(s0 + srow) * 2304 + ch * 8);
    }
    __syncthreads();
    u16* dst = Vt + (long)bh * 64 * 2048 + s0;
    #pragma unroll
    for (int j = 0; j < 2; ++j) {
        int c = tid + j * 256;
        int d = c >> 3, ch = c & 7;
        short8 v;
        #pragma unroll
        for (int e = 0; e < 8; ++e) v[e] = (short)tile[ch * 8 + e][d];
        *(short8*)(dst + (long)d * 2048 + ch * 8) = v;
    }
}

// ---------------- LayerNorm fp32 -> bf16 ----------------
__global__ __launch_bounds__(256) void ln_kernel(const float* __restrict__ x,
                                                 const float* __restrict__ gain,
                                                 const float* __restrict__ beta,
                                                 u16* __restrict__ out) {
    int row = blockIdx.x;
    const float* xr = x + (long)row * 768;
    int tid = threadIdx.x;
    float v[3];
    float s = 0.f, s2 = 0.f;
    for (int j = 0; j < 3; j++) {
        v[j] = xr[tid + 256 * j];
        s += v[j]; s2 += v[j] * v[j];
    }
    for (int off = 32; off; off >>= 1) {
        s  += __shfl_down(s, off);
        s2 += __shfl_down(s2, off);
    }
    __shared__ float ws[8];
    int lane = tid & 63, w = tid >> 6;
    if (lane == 0) { ws[w] = s; ws[4 + w] = s2; }
    __syncthreads();
    s  = ws[0] + ws[1] + ws[2] + ws[3];
    s2 = ws[4] + ws[5] + ws[6] + ws[7];
    float mu  = s * (1.f / 768.f);
    float var = s2 * (1.f / 768.f) - mu * mu;
    float rs  = rsqrtf(var + 1e-5f);
    for (int j = 0; j < 3; j++) {
        int c = tid + 256 * j;
        out[(long)row * 768 + c] = f2bf((v[j] - mu) * rs * gain[c] + beta[c]);
    }
}

// ---------------- bf16 GEMM: C = A[MxK] * Bt[NxK]^T + bias (+epilogue) ----------------
template <int EPI>
__global__ __launch_bounds__(256) void gemm_bf16(const u16* __restrict__ A,
                                                 const u16* __restrict__ Bt,
                                                 const float* __restrict__ bias,
                                                 const float* __restrict__ res,
                                                 void* __restrict__ Cout,
                                                 int M, int N, int K) {
    constexpr int BK = 32;
    __shared__ alignas(16) u16 As[128 * BK];
    __shared__ alignas(16) u16 Bs[128 * BK];
    int tN = blockIdx.x * 128, tM = blockIdx.y * 128;
    int tid = threadIdx.x;
    int wid = tid >> 6, lane = tid & 63;
    int wm = wid >> 1, wn = wid & 1;
    int g = lane >> 4, r = lane & 15;

    f32x4 acc[4][4] = {};

    const u16* Ag = A + (long)(tM + wid * 32 + (lane >> 2)) * K + (lane & 3) * 8;
    const u16* Bg = Bt + (long)(tN + wid * 32 + (lane >> 2)) * K + (lane & 3) * 8;
    u16* Asw = As + wid * 32 * BK;
    u16* Bsw = Bs + wid * 32 * BK;

    for (int k0 = 0; k0 < K; k0 += BK) {
        __syncthreads();
        gload_lds16(Ag + k0, Asw);
        gload_lds16(Ag + (long)16 * K + k0, Asw + 512);
        gload_lds16(Bg + k0, Bsw);
        gload_lds16(Bg + (long)16 * K + k0, Bsw + 512);
        __syncthreads();
        short8 af[4], bf[4];
        #pragma unroll
        for (int mi = 0; mi < 4; mi++)
            af[mi] = *(const short8*)(As + (wm * 64 + mi * 16 + r) * BK + g * 8);
        #pragma unroll
        for (int ni = 0; ni < 4; ni++)
            bf[ni] = *(const short8*)(Bs + (wn * 64 + ni * 16 + r) * BK + g * 8);
        #pragma unroll
        for (int mi = 0; mi < 4; mi++)
            #pragma unroll
            for (int ni = 0; ni < 4; ni++)
                acc[mi][ni] = __builtin_amdgcn_mfma_f32_16x16x32_bf16(af[mi], bf[ni], acc[mi][ni], 0, 0, 0);
    }

    #pragma unroll
    for (int mi = 0; mi < 4; mi++) {
        #pragma unroll
        for (int ni = 0; ni < 4; ni++) {
            int col = tN + wn * 64 + ni * 16 + r;
            float bv = bias[col];
            #pragma unroll
            for (int reg = 0; reg < 4; reg++) {
                int row = tM + wm * 64 + mi * 16 + g * 4 + reg;
                float v = acc[mi][ni][reg] + bv;
                if (EPI == 1) {
                    v += res[(long)row * N + col];
                    ((float*)Cout)[(long)row * N + col] = v;
                } else if (EPI == 2) {
                    v = 0.5f * v * (1.f + erff(v * 0.70710678118f));
                    ((u16*)Cout)[(long)row * N + col] = f2bf(v);
                } else {
                    ((u16*)Cout)[(long)row * N + col] = f2bf(v);
                }
            }
        }
    }
}

// ---------------- flash attention, causal, 4 waves x 32 q-rows (Q-tile 128), KVBLK=64 ----
// Double-buffered K/V staging with counted vmcnt; defer-max rescale.
// qkv bf16 [B][S][2304]; Vt bf16 [B*H][64][2048]; O bf16 [B*S][768]
__global__ __launch_bounds__(256) void attn_kernel(const u16* __restrict__ qkv,
                                                   const u16* __restrict__ Vt,
                                                   u16* __restrict__ O) {
    __shared__ alignas(16) u16 Ks[2 * 64 * 64];
    __shared__ alignas(16) u16 Vs[2 * 64 * 64];
    __shared__ alignas(16) u16 Ps[4 * 32 * 64];
    int flat = blockIdx.x;          // 384 blocks; heavy (long-loop) q-tiles first
    int qi = 15 - flat / 24;
    int bh = flat % 24;
    int b = bh / 12, h = bh % 12;
    int tid = threadIdx.x;
    int w = tid >> 6, lane = tid & 63;
    int g = lane >> 4, r = lane & 15;
    int qt0 = qi * 128;
    int qw0 = qt0 + w * 32;
    const u16* base = qkv + (long)b * 2048 * 2304;
    const u16* Qb = base + h * 64;
    const u16* Kb = base + 768 + h * 64;
    const u16* Vtb = Vt + (long)bh * 64 * 2048;

    short8 qf[2][2];
    #pragma unroll
    for (int fi = 0; fi < 2; ++fi) {
        const u16* qrow = Qb + (long)(qw0 + fi * 16 + r) * 2304;
        qf[fi][0] = *(const short8*)(qrow + 8 * g);
        qf[fi][1] = *(const short8*)(qrow + 32 + 8 * g);
    }
    f32x4 oacc[2][4] = {};
    float mrow[2][4], lrow[2][4];
    #pragma unroll
    for (int fi = 0; fi < 2; ++fi)
        #pragma unroll
        for (int i = 0; i < 4; i++) { mrow[fi][i] = -1e30f; lrow[fi][i] = 0.f; }
    const float SC = 0.125f * 1.44269504f;   // fold log2(e): exp2 domain

    auto stage = [&](int kt) {
        int kv0 = kt * 64;
        u16* kb = Ks + (kt & 1) * 4096;
        u16* vb = Vs + (kt & 1) * 4096;
        #pragma unroll
        for (int j = 0; j < 2; ++j) {
            int c = w * 128 + j * 64 + lane;
            int row = c >> 3;
            int slot = (c & 7) ^ (row & 7);
            gload_lds16(Kb + (long)(kv0 + row) * 2304 + slot * 8, kb + (w * 128 + j * 64) * 8);
            gload_lds16(Vtb + (long)row * 2048 + kv0 + slot * 8, vb + (w * 128 + j * 64) * 8);
        }
    };

    int ktmax = 2 * qi + 2;
    stage(0);
    for (int kt = 0; kt < ktmax; ++kt) {
        int kv0 = kt * 64;
        if (kt + 1 < ktmax) {
            stage(kt + 1);                                   // 4 loads/wave in flight for next tile
            asm volatile("s_waitcnt vmcnt(4)" ::: "memory"); // current tile's loads complete
        } else {
            asm volatile("s_waitcnt vmcnt(0)" ::: "memory");
        }
        __builtin_amdgcn_sched_barrier(0);
        __builtin_amdgcn_s_barrier();                        // all waves' current-tile loads landed
        const u16* kb = Ks + (kt & 1) * 4096;
        const u16* vb = Vs + (kt & 1) * 4096;

        f32x4 sc[2][4] = {};
        float tmax[2][4];
        bool act[2];
        #pragma unroll
        for (int fi = 0; fi < 2; ++fi) {
            act[fi] = kv0 <= qw0 + fi * 16 + 15;
            if (!act[fi]) continue;
            #pragma unroll
            for (int nt = 0; nt < 4; ++nt) {
                #pragma unroll
                for (int kh = 0; kh < 2; ++kh) {
                    short8 bk = *(const short8*)(kb + (nt * 16 + r) * 64 + ((kh * 32 + g * 8) ^ ((r & 7) << 3)));
                    sc[fi][nt] = __builtin_amdgcn_mfma_f32_16x16x32_bf16(qf[fi][kh], bk, sc[fi][nt], 0, 0, 0);
                }
            }
            bool needmask = (kv0 + 63) > (qw0 + fi * 16);
            #pragma unroll
            for (int reg = 0; reg < 4; ++reg) tmax[fi][reg] = -1e30f;
            #pragma unroll
            for (int nt = 0; nt < 4; ++nt)
                #pragma unroll
                for (int reg = 0; reg < 4; ++reg) {
                    float sv = sc[fi][nt][reg] * SC;
                    if (needmask && (kv0 + nt * 16 + r) > (qw0 + fi * 16 + g * 4 + reg)) sv = -1e30f;
                    sc[fi][nt][reg] = sv;
                    tmax[fi][reg] = fmaxf(tmax[fi][reg], sv);
                }
            #pragma unroll
            for (int off = 1; off < 16; off <<= 1)
                #pragma unroll
                for (int reg = 0; reg < 4; ++reg)
                    tmax[fi][reg] = fmaxf(tmax[fi][reg], __shfl_xor(tmax[fi][reg], off));
        }

        // defer-max: only rescale when a row max grew by > 8 (exp2 domain => P <= 256)
        bool need = false;
        #pragma unroll
        for (int fi = 0; fi < 2; ++fi)
            if (act[fi])
                #pragma unroll
                for (int reg = 0; reg < 4; ++reg)
                    need = need || (tmax[fi][reg] > mrow[fi][reg] + 8.f);
        if (__any(need)) {
            #pragma unroll
            for (int fi = 0; fi < 2; ++fi) {
                if (!act[fi]) continue;
                #pragma unroll
                for (int reg = 0; reg < 4; ++reg) {
                    float mnew = fmaxf(mrow[fi][reg], tmax[fi][reg]);
                    float alpha = exp2f(mrow[fi][reg] - mnew);
                    mrow[fi][reg] = mnew;
                    lrow[fi][reg] *= alpha;
                    #pragma unroll
                    for (int dt = 0; dt < 4; ++dt) oacc[fi][dt][reg] *= alpha;
                }
            }
        }

        #pragma unroll
        for (int fi = 0; fi < 2; ++fi) {
            if (!act[fi]) continue;
            float psum[4] = {0.f, 0.f, 0.f, 0.f};
            u16* Pw = Ps + (w * 32 + fi * 16) * 64;
            #pragma unroll
            for (int nt = 0; nt < 4; ++nt)
                #pragma unroll
                for (int reg = 0; reg < 4; ++reg) {
                    float p = exp2f(sc[fi][nt][reg] - mrow[fi][reg]);
                    psum[reg] += p;
                    int row = g * 4 + reg;
                    Pw[row * 64 + ((nt * 16 + r) ^ ((row & 7) << 3))] = f2bf(p);
                }
            #pragma unroll
            for (int off = 1; off < 16; off <<= 1)
                #pragma unroll
                for (int reg = 0; reg < 4; ++reg)
                    psum[reg] += __shfl_xor(psum[reg], off);
            #pragma unroll
            for (int reg = 0; reg < 4; ++reg)
                lrow[fi][reg] += psum[reg];

            short8 pf[2];
            pf[0] = *(const short8*)(Pw + r * 64 + ((g * 8) ^ ((r & 7) << 3)));
            pf[1] = *(const short8*)(Pw + r * 64 + ((32 + g * 8) ^ ((r & 7) << 3)));
            #pragma unroll
            for (int dt = 0; dt < 4; ++dt)
                #pragma unroll
                for (int kc = 0; kc < 2; ++kc) {
                    short8 vf = *(const short8*)(vb + (dt * 16 + r) * 64 + ((kc * 32 + g * 8) ^ ((r & 7) << 3)));
                    oacc[fi][dt] = __builtin_amdgcn_mfma_f32_16x16x32_bf16(pf[kc], vf, oacc[fi][dt], 0, 0, 0);
                }
        }
        __builtin_amdgcn_s_barrier();   // all waves done reading buf[kt&1] before it is restaged
    }

    float inv[2][4];
    #pragma unroll
    for (int fi = 0; fi < 2; ++fi)
        #pragma unroll
        for (int reg = 0; reg < 4; ++reg) inv[fi][reg] = 1.0f / lrow[fi][reg];
    #pragma unroll
    for (int fi = 0; fi < 2; ++fi)
        #pragma unroll
        for (int dt = 0; dt < 4; ++dt)
            #pragma unroll
            for (int reg = 0; reg < 4; ++reg) {
                int q = qw0 + fi * 16 + g * 4 + reg;
                int d = dt * 16 + r;
                O[(long)(b * 2048 + q) * 768 + h * 64 + d] = f2bf(oacc[fi][dt][reg] * inv[fi][reg]);
            }
}

extern "C" void kernel_launch(void* const* d_in, const int* in_sizes, int n_in,
                              void* d_out, int out_size, void* d_ws, size_t ws_size,
                              hipStream_t stream) {
    const float* x     = (const float*)d_in[0];
    const float* ln1_g = (const float*)d_in[1];
    const float* ln1_b = (const float*)d_in[2];
    const float* ln2_g = (const float*)d_in[3];
    const float* ln2_b = (const float*)d_in[4];
    const float* w_qkv = (const float*)d_in[5];
    const float* b_qkv = (const float*)d_in[6];
    const float* w_out = (const float*)d_in[7];
    const float* b_out = (const float*)d_in[8];
    const float* w_fc1 = (const float*)d_in[9];
    const float* b_fc1 = (const float*)d_in[10];
    const float* w_fc2 = (const float*)d_in[11];
    const float* b_fc2 = (const float*)d_in[12];

    char* ws = (char*)d_ws;
    size_t off = 0;
    auto alloc = [&](size_t bytes) { void* p = ws + off; off += (bytes + 255) & ~255ULL; return p; };
    u16* h1    = (u16*)alloc(4096UL * 768 * 2);
    u16* WqkvT = (u16*)alloc(2304UL * 768 * 2);
    u16* WoutT = (u16*)alloc(768UL * 768 * 2);
    u16* Wfc1T = (u16*)alloc(3072UL * 768 * 2);
    u16* Wfc2T = (u16*)alloc(768UL * 3072 * 2);
    u16* qkvb  = (u16*)alloc(4096UL * 2304 * 2);
    u16* Vtb   = (u16*)alloc(24UL * 64 * 2048 * 2);
    u16* Ob    = (u16*)alloc(4096UL * 768 * 2);
    float* x2  = (float*)alloc(4096UL * 768 * 4);
    u16* h2    = (u16*)alloc(4096UL * 768 * 2);
    u16* gbuf  = (u16*)alloc(4096UL * 3072 * 2);

    transpose_w<<<dim3(2304 / 32, 768 / 32), 256, 0, stream>>>(w_qkv, WqkvT, 768, 2304);
    transpose_w<<<dim3(768 / 32, 768 / 32), 256, 0, stream>>>(w_out, WoutT, 768, 768);
    transpose_w<<<dim3(3072 / 32, 768 / 32), 256, 0, stream>>>(w_fc1, Wfc1T, 768, 3072);
    transpose_w<<<dim3(768 / 32, 3072 / 32), 256, 0, stream>>>(w_fc2, Wfc2T, 3072, 768);

    ln_kernel<<<4096, 256, 0, stream>>>(x, ln1_g, ln1_b, h1);
    gemm_bf16<0><<<dim3(2304 / 128, 4096 / 128), 256, 0, stream>>>(h1, WqkvT, b_qkv, nullptr, qkvb, 4096, 2304, 768);
    transpose_v<<<dim3(32, 24), 256, 0, stream>>>(qkvb, Vtb);
    attn_kernel<<<dim3(384), 256, 0, stream>>>(qkvb, Vtb, Ob);
    gemm_bf16<1><<<dim3(768 / 128, 4096 / 128), 256, 0, stream>>>(Ob, WoutT, b_out, x, x2, 4096, 768, 768);
    ln_kernel<<<4096, 256, 0, stream>>>(x2, ln2_g, ln2_b, h2);
    gemm_bf16<2><<<dim3(3072 / 128, 4096 / 128), 256, 0, stream>>>(h2, Wfc1T, b_fc1, nullptr, gbuf, 4096, 3072, 768);
    gemm_bf16<1><<<dim3(768 / 128, 4096 / 128), 256, 0, stream>>>(gbuf, Wfc2T, b_fc2, x2, (float*)d_out, 4096, 768, 3072);
}

// Round 4
// 272.253 us; speedup vs baseline: 1.4185x; 1.1192x over previous
//
#include <hip/hip_runtime.h>
#include <hip/hip_bf16.h>

typedef unsigned short u16;
typedef unsigned int u32;
typedef unsigned char u8;
using short8 = __attribute__((ext_vector_type(8))) short;
using f32x4  = __attribute__((ext_vector_type(4))) float;

__device__ __forceinline__ u16 f2bf(float f) {
    __hip_bfloat16 h = __float2bfloat16(f);
    union { __hip_bfloat16 h; u16 u; } cv; cv.h = h; return cv.u;
}
__device__ __forceinline__ float bf2f(u16 u) {
    union { u32 u; float f; } cv; cv.u = ((u32)u) << 16; return cv.f;
}

__device__ __forceinline__ void gload_lds16(const void* g, void* l) {
    __builtin_amdgcn_global_load_lds(
        (const __attribute__((address_space(1))) u32*)g,
        (__attribute__((address_space(3))) u32*)l, 16, 0, 0);
}

// ---------------- transpose + fp32->bf16 convert: W[K][N] -> Wt[N][K] ----------------
__global__ __launch_bounds__(256) void transpose_w(const float* __restrict__ W,
                                                   u16* __restrict__ Wt, int K, int N) {
    __shared__ float tile[32][33];
    int n0 = blockIdx.x * 32, k0 = blockIdx.y * 32;
    int tx = threadIdx.x & 31, ty = threadIdx.x >> 5;
    for (int i = 0; i < 4; i++) {
        int k = ty + i * 8;
        tile[k][tx] = W[(long)(k0 + k) * N + n0 + tx];
    }
    __syncthreads();
    for (int i = 0; i < 4; i++) {
        int n = ty + i * 8;
        Wt[(long)(n0 + n) * K + k0 + tx] = f2bf(tile[tx][n]);
    }
}

// ---------------- V transpose: qkv[B][S][2304] (V slice) -> Vt[B*H][64][2048] ------------
__global__ __launch_bounds__(256) void transpose_v(const u16* __restrict__ qkv,
                                                   u16* __restrict__ Vt) {
    __shared__ u16 tile[64][72];
    int s0 = blockIdx.x * 64;
    int bh = blockIdx.y;
    int b = bh / 12, h = bh % 12;
    int tid = threadIdx.x;
    const u16* src = qkv + (long)b * 2048 * 2304 + 1536 + h * 64;
    #pragma unroll
    for (int j = 0; j < 2; ++j) {
        int c = tid + j * 256;
        int srow = c >> 3, ch = c & 7;
        *(short8*)&tile[srow][ch * 8] = *(const short8*)(src + (long)(s0 + srow) * 2304 + ch * 8);
    }
    __syncthreads();
    u16* dst = Vt + (long)bh * 64 * 2048 + s0;
    #pragma unroll
    for (int j = 0; j < 2; ++j) {
        int c = tid + j * 256;
        int d = c >> 3, ch = c & 7;
        short8 v;
        #pragma unroll
        for (int e = 0; e < 8; ++e) v[e] = (short)tile[ch * 8 + e][d];
        *(short8*)(dst + (long)d * 2048 + ch * 8) = v;
    }
}

// ---------------- LayerNorm fp32 -> bf16 ----------------
__global__ __launch_bounds__(256) void ln_kernel(const float* __restrict__ x,
                                                 const float* __restrict__ gain,
                                                 const float* __restrict__ beta,
                                                 u16* __restrict__ out) {
    int row = blockIdx.x;
    const float* xr = x + (long)row * 768;
    int tid = threadIdx.x;
    float v[3];
    float s = 0.f, s2 = 0.f;
    for (int j = 0; j < 3; j++) {
        v[j] = xr[tid + 256 * j];
        s += v[j]; s2 += v[j] * v[j];
    }
    for (int off = 32; off; off >>= 1) {
        s  += __shfl_down(s, off);
        s2 += __shfl_down(s2, off);
    }
    __shared__ float ws[8];
    int lane = tid & 63, w = tid >> 6;
    if (lane == 0) { ws[w] = s; ws[4 + w] = s2; }
    __syncthreads();
    s  = ws[0] + ws[1] + ws[2] + ws[3];
    s2 = ws[4] + ws[5] + ws[6] + ws[7];
    float mu  = s * (1.f / 768.f);
    float var = s2 * (1.f / 768.f) - mu * mu;
    float rs  = rsqrtf(var + 1e-5f);
    for (int j = 0; j < 3; j++) {
        int c = tid + 256 * j;
        out[(long)row * 768 + c] = f2bf((v[j] - mu) * rs * gain[c] + beta[c]);
    }
}

// ---------------- bf16 GEMM: C = A[MxK] * Bt[NxK]^T + bias (+epilogue) ----------------
template <int EPI>
__global__ __launch_bounds__(256) void gemm_bf16(const u16* __restrict__ A,
                                                 const u16* __restrict__ Bt,
                                                 const float* __restrict__ bias,
                                                 const float* __restrict__ res,
                                                 void* __restrict__ Cout,
                                                 int M, int N, int K) {
    constexpr int BK = 32;
    __shared__ alignas(16) u16 As[128 * BK];
    __shared__ alignas(16) u16 Bs[128 * BK];
    int tN = blockIdx.x * 128, tM = blockIdx.y * 128;
    int tid = threadIdx.x;
    int wid = tid >> 6, lane = tid & 63;
    int wm = wid >> 1, wn = wid & 1;
    int g = lane >> 4, r = lane & 15;

    f32x4 acc[4][4] = {};

    const u16* Ag = A + (long)(tM + wid * 32 + (lane >> 2)) * K + (lane & 3) * 8;
    const u16* Bg = Bt + (long)(tN + wid * 32 + (lane >> 2)) * K + (lane & 3) * 8;
    u16* Asw = As + wid * 32 * BK;
    u16* Bsw = Bs + wid * 32 * BK;

    for (int k0 = 0; k0 < K; k0 += BK) {
        __syncthreads();
        gload_lds16(Ag + k0, Asw);
        gload_lds16(Ag + (long)16 * K + k0, Asw + 512);
        gload_lds16(Bg + k0, Bsw);
        gload_lds16(Bg + (long)16 * K + k0, Bsw + 512);
        __syncthreads();
        short8 af[4], bf[4];
        #pragma unroll
        for (int mi = 0; mi < 4; mi++)
            af[mi] = *(const short8*)(As + (wm * 64 + mi * 16 + r) * BK + g * 8);
        #pragma unroll
        for (int ni = 0; ni < 4; ni++)
            bf[ni] = *(const short8*)(Bs + (wn * 64 + ni * 16 + r) * BK + g * 8);
        #pragma unroll
        for (int mi = 0; mi < 4; mi++)
            #pragma unroll
            for (int ni = 0; ni < 4; ni++)
                acc[mi][ni] = __builtin_amdgcn_mfma_f32_16x16x32_bf16(af[mi], bf[ni], acc[mi][ni], 0, 0, 0);
    }

    #pragma unroll
    for (int mi = 0; mi < 4; mi++) {
        #pragma unroll
        for (int ni = 0; ni < 4; ni++) {
            int col = tN + wn * 64 + ni * 16 + r;
            float bv = bias[col];
            #pragma unroll
            for (int reg = 0; reg < 4; reg++) {
                int row = tM + wm * 64 + mi * 16 + g * 4 + reg;
                float v = acc[mi][ni][reg] + bv;
                if (EPI == 1) {
                    v += res[(long)row * N + col];
                    ((float*)Cout)[(long)row * N + col] = v;
                } else if (EPI == 2) {
                    v = 0.5f * v * (1.f + erff(v * 0.70710678118f));
                    ((u16*)Cout)[(long)row * N + col] = f2bf(v);
                } else {
                    ((u16*)Cout)[(long)row * N + col] = f2bf(v);
                }
            }
        }
    }
}

// ---------------- split-K flash attention (causal) ----------------
// KV split into 512-wide chunks; block = (slot, bh); slot -> (qi, chunk) via tables,
// heavy-first. Writes unnormalized partial O (bf16) and (m,l) per row per chunk.
// qkv bf16 [B][S][2304]; Vt bf16 [B*H][64][2048]
// Opart bf16 [4][24][2048][64]; Ml fp32 [4][24][2048][2]
__device__ __constant__ u8 SLOT_QI[40] = {
    15,15,15,15, 14,14,14, 13,13,13, 12,12,12, 11,11,11, 10,10, 9,9, 8,8, 7,7, 6, 5, 4, 3,
    14,10,6,2,  13,9,5,1,  12,8,4,0 };
__device__ __constant__ u8 SLOT_C[40] = {
    0,1,2,3, 0,1,2, 0,1,2, 0,1,2, 0,1,2, 0,1, 0,1, 0,1, 0,1, 0, 0, 0, 0,
    3,2,1,0, 3,2,1,0, 3,2,1,0 };

__global__ __launch_bounds__(256) void attn_kernel(const u16* __restrict__ qkv,
                                                   const u16* __restrict__ Vt,
                                                   u16* __restrict__ Opart,
                                                   float* __restrict__ Ml) {
    __shared__ alignas(16) u16 Ks[2 * 64 * 64];
    __shared__ alignas(16) u16 Vs[2 * 64 * 64];
    __shared__ alignas(16) u16 Ps[4 * 32 * 64];
    int flat = blockIdx.x;
    int s = flat / 24, bh = flat % 24;
    int qi = SLOT_QI[s], c = SLOT_C[s];
    int b = bh / 12, h = bh % 12;
    int tid = threadIdx.x;
    int w = tid >> 6, lane = tid & 63;
    int g = lane >> 4, r = lane & 15;
    int qt0 = qi * 128;
    int qw0 = qt0 + w * 32;
    int kvbase = c * 512;
    int nit = (c < (qi >> 2)) ? 8 : (2 * (qi & 3) + 2);
    const u16* base = qkv + (long)b * 2048 * 2304;
    const u16* Qb = base + h * 64;
    const u16* Kb = base + 768 + h * 64;
    const u16* Vtb = Vt + (long)bh * 64 * 2048;

    short8 qf[2][2];
    #pragma unroll
    for (int fi = 0; fi < 2; ++fi) {
        const u16* qrow = Qb + (long)(qw0 + fi * 16 + r) * 2304;
        qf[fi][0] = *(const short8*)(qrow + 8 * g);
        qf[fi][1] = *(const short8*)(qrow + 32 + 8 * g);
    }
    f32x4 oacc[2][4] = {};
    float mrow[2][4], lrow[2][4];
    #pragma unroll
    for (int fi = 0; fi < 2; ++fi)
        #pragma unroll
        for (int i = 0; i < 4; i++) { mrow[fi][i] = -1e30f; lrow[fi][i] = 0.f; }
    const float SC = 0.125f * 1.44269504f;   // exp2 domain

    auto stage = [&](int kt) {
        int kv0 = kvbase + kt * 64;
        u16* kb = Ks + (kt & 1) * 4096;
        u16* vb = Vs + (kt & 1) * 4096;
        #pragma unroll
        for (int j = 0; j < 2; ++j) {
            int cc = w * 128 + j * 64 + lane;
            int row = cc >> 3;
            int slot = (cc & 7) ^ (row & 7);
            gload_lds16(Kb + (long)(kv0 + row) * 2304 + slot * 8, kb + (w * 128 + j * 64) * 8);
            gload_lds16(Vtb + (long)row * 2048 + kv0 + slot * 8, vb + (w * 128 + j * 64) * 8);
        }
    };

    stage(0);
    for (int kt = 0; kt < nit; ++kt) {
        int kv0 = kvbase + kt * 64;
        if (kt + 1 < nit) {
            stage(kt + 1);
            asm volatile("s_waitcnt vmcnt(4)" ::: "memory");
        } else {
            asm volatile("s_waitcnt vmcnt(0)" ::: "memory");
        }
        __builtin_amdgcn_sched_barrier(0);
        __builtin_amdgcn_s_barrier();
        const u16* kb = Ks + (kt & 1) * 4096;
        const u16* vb = Vs + (kt & 1) * 4096;

        f32x4 sc[2][4] = {};
        float tmax[2][4];
        bool act[2];
        #pragma unroll
        for (int fi = 0; fi < 2; ++fi) {
            act[fi] = kv0 <= qw0 + fi * 16 + 15;
            if (!act[fi]) continue;
            #pragma unroll
            for (int nt = 0; nt < 4; ++nt) {
                #pragma unroll
                for (int kh = 0; kh < 2; ++kh) {
                    short8 bk = *(const short8*)(kb + (nt * 16 + r) * 64 + ((kh * 32 + g * 8) ^ ((r & 7) << 3)));
                    sc[fi][nt] = __builtin_amdgcn_mfma_f32_16x16x32_bf16(qf[fi][kh], bk, sc[fi][nt], 0, 0, 0);
                }
            }
            bool needmask = (kv0 + 63) > (qw0 + fi * 16);
            #pragma unroll
            for (int reg = 0; reg < 4; ++reg) tmax[fi][reg] = -1e30f;
            #pragma unroll
            for (int nt = 0; nt < 4; ++nt)
                #pragma unroll
                for (int reg = 0; reg < 4; ++reg) {
                    float sv = sc[fi][nt][reg] * SC;
                    if (needmask && (kv0 + nt * 16 + r) > (qw0 + fi * 16 + g * 4 + reg)) sv = -1e30f;
                    sc[fi][nt][reg] = sv;
                    tmax[fi][reg] = fmaxf(tmax[fi][reg], sv);
                }
            #pragma unroll
            for (int off = 1; off < 16; off <<= 1)
                #pragma unroll
                for (int reg = 0; reg < 4; ++reg)
                    tmax[fi][reg] = fmaxf(tmax[fi][reg], __shfl_xor(tmax[fi][reg], off));
        }

        bool need = false;
        #pragma unroll
        for (int fi = 0; fi < 2; ++fi)
            if (act[fi])
                #pragma unroll
                for (int reg = 0; reg < 4; ++reg)
                    need = need || (tmax[fi][reg] > mrow[fi][reg] + 8.f);
        if (__any(need)) {
            #pragma unroll
            for (int fi = 0; fi < 2; ++fi) {
                if (!act[fi]) continue;
                #pragma unroll
                for (int reg = 0; reg < 4; ++reg) {
                    float mnew = fmaxf(mrow[fi][reg], tmax[fi][reg]);
                    float alpha = exp2f(mrow[fi][reg] - mnew);
                    mrow[fi][reg] = mnew;
                    lrow[fi][reg] *= alpha;
                    #pragma unroll
                    for (int dt = 0; dt < 4; ++dt) oacc[fi][dt][reg] *= alpha;
                }
            }
        }

        #pragma unroll
        for (int fi = 0; fi < 2; ++fi) {
            if (!act[fi]) continue;
            float psum[4] = {0.f, 0.f, 0.f, 0.f};
            u16* Pw = Ps + (w * 32 + fi * 16) * 64;
            #pragma unroll
            for (int nt = 0; nt < 4; ++nt)
                #pragma unroll
                for (int reg = 0; reg < 4; ++reg) {
                    float p = exp2f(sc[fi][nt][reg] - mrow[fi][reg]);
                    psum[reg] += p;
                    int row = g * 4 + reg;
                    Pw[row * 64 + ((nt * 16 + r) ^ ((row & 7) << 3))] = f2bf(p);
                }
            #pragma unroll
            for (int off = 1; off < 16; off <<= 1)
                #pragma unroll
                for (int reg = 0; reg < 4; ++reg)
                    psum[reg] += __shfl_xor(psum[reg], off);
            #pragma unroll
            for (int reg = 0; reg < 4; ++reg)
                lrow[fi][reg] += psum[reg];

            short8 pf[2];
            pf[0] = *(const short8*)(Pw + r * 64 + ((g * 8) ^ ((r & 7) << 3)));
            pf[1] = *(const short8*)(Pw + r * 64 + ((32 + g * 8) ^ ((r & 7) << 3)));
            #pragma unroll
            for (int dt = 0; dt < 4; ++dt)
                #pragma unroll
                for (int kc = 0; kc < 2; ++kc) {
                    short8 vf = *(const short8*)(vb + (dt * 16 + r) * 64 + ((kc * 32 + g * 8) ^ ((r & 7) << 3)));
                    oacc[fi][dt] = __builtin_amdgcn_mfma_f32_16x16x32_bf16(pf[kc], vf, oacc[fi][dt], 0, 0, 0);
                }
        }
        __builtin_amdgcn_s_barrier();
    }

    long pbase = ((long)c * 24 + bh) * 2048;
    #pragma unroll
    for (int fi = 0; fi < 2; ++fi)
        #pragma unroll
        for (int dt = 0; dt < 4; ++dt)
            #pragma unroll
            for (int reg = 0; reg < 4; ++reg) {
                int q = qw0 + fi * 16 + g * 4 + reg;
                int d = dt * 16 + r;
                Opart[(pbase + q) * 64 + d] = f2bf(oacc[fi][dt][reg]);
            }
    if (r == 0) {
        #pragma unroll
        for (int fi = 0; fi < 2; ++fi)
            #pragma unroll
            for (int reg = 0; reg < 4; ++reg) {
                int q = qw0 + fi * 16 + g * 4 + reg;
                Ml[(pbase + q) * 2]     = mrow[fi][reg];
                Ml[(pbase + q) * 2 + 1] = lrow[fi][reg];
            }
    }
}

// ---------------- combine split-K partials -> Ob bf16 [B*S][768] ----------------
__global__ __launch_bounds__(256) void attn_combine(const u16* __restrict__ Opart,
                                                    const float* __restrict__ Ml,
                                                    u16* __restrict__ Ob) {
    int bh = blockIdx.y;
    int b = bh / 12, h = bh % 12;
    int q = blockIdx.x * 4 + (threadIdx.x >> 6);
    int d = threadIdx.x & 63;
    int qi = q >> 7;
    int nact = (qi >> 2) + 1;
    float mv[4], lv[4];
    float M = -1e30f;
    for (int c = 0; c < nact; ++c) {
        long base = ((long)c * 24 + bh) * 2048 + q;
        mv[c] = Ml[base * 2];
        lv[c] = Ml[base * 2 + 1];
        M = fmaxf(M, mv[c]);
    }
    float denom = 0.f, val = 0.f;
    for (int c = 0; c < nact; ++c) {
        float wgt = exp2f(mv[c] - M);
        denom += lv[c] * wgt;
        val += wgt * bf2f(Opart[(((long)c * 24 + bh) * 2048 + q) * 64 + d]);
    }
    Ob[((long)b * 2048 + q) * 768 + h * 64 + d] = f2bf(val / denom);
}

extern "C" void kernel_launch(void* const* d_in, const int* in_sizes, int n_in,
                              void* d_out, int out_size, void* d_ws, size_t ws_size,
                              hipStream_t stream) {
    const float* x     = (const float*)d_in[0];
    const float* ln1_g = (const float*)d_in[1];
    const float* ln1_b = (const float*)d_in[2];
    const float* ln2_g = (const float*)d_in[3];
    const float* ln2_b = (const float*)d_in[4];
    const float* w_qkv = (const float*)d_in[5];
    const float* b_qkv = (const float*)d_in[6];
    const float* w_out = (const float*)d_in[7];
    const float* b_out = (const float*)d_in[8];
    const float* w_fc1 = (const float*)d_in[9];
    const float* b_fc1 = (const float*)d_in[10];
    const float* w_fc2 = (const float*)d_in[11];
    const float* b_fc2 = (const float*)d_in[12];

    char* ws = (char*)d_ws;
    size_t off = 0;
    auto alloc = [&](size_t bytes) { void* p = ws + off; off += (bytes + 255) & ~255ULL; return p; };
    u16* h1    = (u16*)alloc(4096UL * 768 * 2);
    u16* WqkvT = (u16*)alloc(2304UL * 768 * 2);
    u16* WoutT = (u16*)alloc(768UL * 768 * 2);
    u16* Wfc1T = (u16*)alloc(3072UL * 768 * 2);
    u16* Wfc2T = (u16*)alloc(768UL * 3072 * 2);
    u16* qkvb  = (u16*)alloc(4096UL * 2304 * 2);
    u16* Vtb   = (u16*)alloc(24UL * 64 * 2048 * 2);
    u16* Ob    = (u16*)alloc(4096UL * 768 * 2);
    float* x2  = (float*)alloc(4096UL * 768 * 4);
    // pool shared (time-disjoint): [h2 (6.3MB) | gbuf (25.2MB)]  vs  [Opart (25.2MB) | Ml (1.6MB)]
    char* pool = (char*)alloc(4096UL * 768 * 2 + 4096UL * 3072 * 2);
    u16* h2      = (u16*)pool;
    u16* gbuf    = (u16*)(pool + 4096UL * 768 * 2);
    u16* Opart   = (u16*)pool;
    float* Ml    = (float*)(pool + 4UL * 24 * 2048 * 64 * 2);

    transpose_w<<<dim3(2304 / 32, 768 / 32), 256, 0, stream>>>(w_qkv, WqkvT, 768, 2304);
    transpose_w<<<dim3(768 / 32, 768 / 32), 256, 0, stream>>>(w_out, WoutT, 768, 768);
    transpose_w<<<dim3(3072 / 32, 768 / 32), 256, 0, stream>>>(w_fc1, Wfc1T, 768, 3072);
    transpose_w<<<dim3(768 / 32, 3072 / 32), 256, 0, stream>>>(w_fc2, Wfc2T, 3072, 768);

    ln_kernel<<<4096, 256, 0, stream>>>(x, ln1_g, ln1_b, h1);
    gemm_bf16<0><<<dim3(2304 / 128, 4096 / 128), 256, 0, stream>>>(h1, WqkvT, b_qkv, nullptr, qkvb, 4096, 2304, 768);
    transpose_v<<<dim3(32, 24), 256, 0, stream>>>(qkvb, Vtb);
    attn_kernel<<<dim3(960), 256, 0, stream>>>(qkvb, Vtb, Opart, Ml);
    attn_combine<<<dim3(512, 24), 256, 0, stream>>>(Opart, Ml, Ob);
    gemm_bf16<1><<<dim3(768 / 128, 4096 / 128), 256, 0, stream>>>(Ob, WoutT, b_out, x, x2, 4096, 768, 768);
    ln_kernel<<<4096, 256, 0, stream>>>(x2, ln2_g, ln2_b, h2);
    gemm_bf16<2><<<dim3(3072 / 128, 4096 / 128), 256, 0, stream>>>(h2, Wfc1T, b_fc1, nullptr, gbuf, 4096, 3072, 768);
    gemm_bf16<1><<<dim3(768 / 128, 4096 / 128), 256, 0, stream>>>(gbuf, Wfc2T, b_fc2, x2, (float*)d_out, 4096, 768, 3072);
}

// Round 5
// 242.582 us; speedup vs baseline: 1.5920x; 1.1223x over previous
//
#include <hip/hip_runtime.h>
#include <hip/hip_bf16.h>

typedef unsigned short u16;
typedef unsigned int u32;
typedef unsigned char u8;
using short8 = __attribute__((ext_vector_type(8))) short;
using f32x4  = __attribute__((ext_vector_type(4))) float;
using float4v = __attribute__((ext_vector_type(4))) float;

__device__ __forceinline__ u16 f2bf(float f) {
    __hip_bfloat16 h = __float2bfloat16(f);
    union { __hip_bfloat16 h; u16 u; } cv; cv.h = h; return cv.u;
}
__device__ __forceinline__ float bf2f(u16 u) {
    union { u32 u; float f; } cv; cv.u = ((u32)u) << 16; return cv.f;
}

__device__ __forceinline__ void gload_lds16(const void* g, void* l) {
    __builtin_amdgcn_global_load_lds(
        (const __attribute__((address_space(1))) u32*)g,
        (__attribute__((address_space(3))) u32*)l, 16, 0, 0);
}

// ---------------- transpose + fp32->bf16 convert: W[K][N] -> Wt[N][K] ----------------
__global__ __launch_bounds__(256) void transpose_w(const float* __restrict__ W,
                                                   u16* __restrict__ Wt, int K, int N) {
    __shared__ float tile[32][33];
    int n0 = blockIdx.x * 32, k0 = blockIdx.y * 32;
    int tx = threadIdx.x & 31, ty = threadIdx.x >> 5;
    for (int i = 0; i < 4; i++) {
        int k = ty + i * 8;
        tile[k][tx] = W[(long)(k0 + k) * N + n0 + tx];
    }
    __syncthreads();
    for (int i = 0; i < 4; i++) {
        int n = ty + i * 8;
        Wt[(long)(n0 + n) * K + k0 + tx] = f2bf(tile[tx][n]);
    }
}

// ---------------- V transpose: qkv[B][S][2304] (V slice) -> Vt[B*H][64][2048] ------------
__global__ __launch_bounds__(256) void transpose_v(const u16* __restrict__ qkv,
                                                   u16* __restrict__ Vt) {
    __shared__ u16 tile[64][72];
    int s0 = blockIdx.x * 64;
    int bh = blockIdx.y;
    int b = bh / 12, h = bh % 12;
    int tid = threadIdx.x;
    const u16* src = qkv + (long)b * 2048 * 2304 + 1536 + h * 64;
    #pragma unroll
    for (int j = 0; j < 2; ++j) {
        int c = tid + j * 256;
        int srow = c >> 3, ch = c & 7;
        *(short8*)&tile[srow][ch * 8] = *(const short8*)(src + (long)(s0 + srow) * 2304 + ch * 8);
    }
    __syncthreads();
    u16* dst = Vt + (long)bh * 64 * 2048 + s0;
    #pragma unroll
    for (int j = 0; j < 2; ++j) {
        int c = tid + j * 256;
        int d = c >> 3, ch = c & 7;
        short8 v;
        #pragma unroll
        for (int e = 0; e < 8; ++e) v[e] = (short)tile[ch * 8 + e][d];
        *(short8*)(dst + (long)d * 2048 + ch * 8) = v;
    }
}

// ---------------- LayerNorm fp32 -> bf16 ----------------
__global__ __launch_bounds__(256) void ln_kernel(const float* __restrict__ x,
                                                 const float* __restrict__ gain,
                                                 const float* __restrict__ beta,
                                                 u16* __restrict__ out) {
    int row = blockIdx.x;
    const float* xr = x + (long)row * 768;
    int tid = threadIdx.x;
    float v[3];
    float s = 0.f, s2 = 0.f;
    for (int j = 0; j < 3; j++) {
        v[j] = xr[tid + 256 * j];
        s += v[j]; s2 += v[j] * v[j];
    }
    for (int off = 32; off; off >>= 1) {
        s  += __shfl_down(s, off);
        s2 += __shfl_down(s2, off);
    }
    __shared__ float ws[8];
    int lane = tid & 63, w = tid >> 6;
    if (lane == 0) { ws[w] = s; ws[4 + w] = s2; }
    __syncthreads();
    s  = ws[0] + ws[1] + ws[2] + ws[3];
    s2 = ws[4] + ws[5] + ws[6] + ws[7];
    float mu  = s * (1.f / 768.f);
    float var = s2 * (1.f / 768.f) - mu * mu;
    float rs  = rsqrtf(var + 1e-5f);
    for (int j = 0; j < 3; j++) {
        int c = tid + 256 * j;
        out[(long)row * 768 + c] = f2bf((v[j] - mu) * rs * gain[c] + beta[c]);
    }
}

// ---------------- bf16 GEMM v2: 128x128 tile, BK=64, double-buffered counted-vmcnt ------
// C = A[M x K(lda)] * Bt[N x K(ldb)]^T (+bias/epilogue). blockIdx.z selects K-chunk:
// A/Bt advance z*K cols; output -> Cout0 (z=0) or Cout1 (z=1).
// EPI 0: bias->bf16; 1: bias+residual->fp32; 2: bias+gelu->bf16; 3: raw fp32 partial.
template <int EPI>
__global__ __launch_bounds__(256) void gemm_bf16(const u16* __restrict__ A, int lda,
                                                 const u16* __restrict__ Bt, int ldb,
                                                 const float* __restrict__ bias,
                                                 const float* __restrict__ res,
                                                 void* __restrict__ Cout0,
                                                 void* __restrict__ Cout1,
                                                 int M, int N, int K) {
    __shared__ alignas(16) u16 As[2][128 * 64];
    __shared__ alignas(16) u16 Bs[2][128 * 64];
    int tN = blockIdx.x * 128, tM = blockIdx.y * 128;
    int z = blockIdx.z;
    const u16* Ab = A + (long)z * K;
    const u16* Bb = Bt + (long)z * K;
    void* Cw = z ? Cout1 : Cout0;
    int tid = threadIdx.x;
    int wid = tid >> 6, lane = tid & 63;
    int wm = wid >> 1, wn = wid & 1;
    int g = lane >> 4, r = lane & 15;
    int row0 = tid >> 3, ch = tid & 7;

    f32x4 acc[4][4] = {};
    int KT = K >> 6;

    auto stage = [&](int kt) {
        int k0 = kt << 6;
        u16* ab = As[kt & 1];
        u16* bb = Bs[kt & 1];
        #pragma unroll
        for (int p = 0; p < 4; ++p) {
            int row = p * 32 + row0;
            int slot = ch ^ (row & 7);
            gload_lds16(Ab + (long)(tM + row) * lda + k0 + slot * 8, ab + (p * 256 + wid * 64) * 8);
        }
        #pragma unroll
        for (int p = 0; p < 4; ++p) {
            int row = p * 32 + row0;
            int slot = ch ^ (row & 7);
            gload_lds16(Bb + (long)(tN + row) * ldb + k0 + slot * 8, bb + (p * 256 + wid * 64) * 8);
        }
    };

    stage(0);
    for (int kt = 0; kt < KT; ++kt) {
        if (kt + 1 < KT) {
            stage(kt + 1);
            asm volatile("s_waitcnt vmcnt(8)" ::: "memory");   // stage(kt)'s 8 loads done
        } else {
            asm volatile("s_waitcnt vmcnt(0)" ::: "memory");
        }
        __builtin_amdgcn_sched_barrier(0);
        __builtin_amdgcn_s_barrier();
        const u16* ab = As[kt & 1];
        const u16* bb = Bs[kt & 1];

        short8 af[2][4], bf[2][4];
        #pragma unroll
        for (int kh = 0; kh < 2; ++kh)
            #pragma unroll
            for (int mi = 0; mi < 4; ++mi) {
                int row = wm * 64 + mi * 16 + r;
                af[kh][mi] = *(const short8*)(ab + row * 64 + (((kh * 4 + g) ^ (row & 7)) * 8));
            }
        #pragma unroll
        for (int kh = 0; kh < 2; ++kh)
            #pragma unroll
            for (int ni = 0; ni < 4; ++ni) {
                int row = wn * 64 + ni * 16 + r;
                bf[kh][ni] = *(const short8*)(bb + row * 64 + (((kh * 4 + g) ^ (row & 7)) * 8));
            }
        #pragma unroll
        for (int kh = 0; kh < 2; ++kh)
            #pragma unroll
            for (int mi = 0; mi < 4; ++mi)
                #pragma unroll
                for (int ni = 0; ni < 4; ++ni)
                    acc[mi][ni] = __builtin_amdgcn_mfma_f32_16x16x32_bf16(af[kh][mi], bf[kh][ni], acc[mi][ni], 0, 0, 0);
        __builtin_amdgcn_s_barrier();   // all waves done reading buf before restage
    }

    #pragma unroll
    for (int mi = 0; mi < 4; mi++) {
        #pragma unroll
        for (int ni = 0; ni < 4; ni++) {
            int col = tN + wn * 64 + ni * 16 + r;
            float bv = (EPI == 3) ? 0.f : bias[col];
            #pragma unroll
            for (int reg = 0; reg < 4; reg++) {
                int row = tM + wm * 64 + mi * 16 + g * 4 + reg;
                float v = acc[mi][ni][reg] + bv;
                if (EPI == 1) {
                    v += res[(long)row * N + col];
                    ((float*)Cw)[(long)row * N + col] = v;
                } else if (EPI == 2) {
                    v = 0.5f * v * (1.f + erff(v * 0.70710678118f));
                    ((u16*)Cw)[(long)row * N + col] = f2bf(v);
                } else if (EPI == 3) {
                    ((float*)Cw)[(long)row * N + col] = v;
                } else {
                    ((u16*)Cw)[(long)row * N + col] = f2bf(v);
                }
            }
        }
    }
}

// ---------------- fc2 split-K combine: out = P0 + P1 + bias + res (fp32) ----------------
__global__ __launch_bounds__(192) void fc2_combine(const float* __restrict__ P0,
                                                   const float* __restrict__ P1,
                                                   const float* __restrict__ bias,
                                                   const float* __restrict__ res,
                                                   float* __restrict__ out) {
    long row = blockIdx.x;
    int c = threadIdx.x * 4;
    long i = row * 768 + c;
    float4v a = *(const float4v*)(P0 + i);
    float4v b = *(const float4v*)(P1 + i);
    float4v bs = *(const float4v*)(bias + c);
    float4v rr = *(const float4v*)(res + i);
    float4v o = a + b + bs + rr;
    *(float4v*)(out + i) = o;
}

// ---------------- split-K flash attention (causal) ----------------
__device__ __constant__ u8 SLOT_QI[40] = {
    15,15,15,15, 14,14,14, 13,13,13, 12,12,12, 11,11,11, 10,10, 9,9, 8,8, 7,7, 6, 5, 4, 3,
    14,10,6,2,  13,9,5,1,  12,8,4,0 };
__device__ __constant__ u8 SLOT_C[40] = {
    0,1,2,3, 0,1,2, 0,1,2, 0,1,2, 0,1,2, 0,1, 0,1, 0,1, 0,1, 0, 0, 0, 0,
    3,2,1,0, 3,2,1,0, 3,2,1,0 };

__global__ __launch_bounds__(256) void attn_kernel(const u16* __restrict__ qkv,
                                                   const u16* __restrict__ Vt,
                                                   u16* __restrict__ Opart,
                                                   float* __restrict__ Ml) {
    __shared__ alignas(16) u16 Ks[2 * 64 * 64];
    __shared__ alignas(16) u16 Vs[2 * 64 * 64];
    __shared__ alignas(16) u16 Ps[4 * 32 * 64];
    int flat = blockIdx.x;
    int s = flat / 24, bh = flat % 24;
    int qi = SLOT_QI[s], c = SLOT_C[s];
    int b = bh / 12, h = bh % 12;
    int tid = threadIdx.x;
    int w = tid >> 6, lane = tid & 63;
    int g = lane >> 4, r = lane & 15;
    int qt0 = qi * 128;
    int qw0 = qt0 + w * 32;
    int kvbase = c * 512;
    int nit = (c < (qi >> 2)) ? 8 : (2 * (qi & 3) + 2);
    const u16* base = qkv + (long)b * 2048 * 2304;
    const u16* Qb = base + h * 64;
    const u16* Kb = base + 768 + h * 64;
    const u16* Vtb = Vt + (long)bh * 64 * 2048;

    short8 qf[2][2];
    #pragma unroll
    for (int fi = 0; fi < 2; ++fi) {
        const u16* qrow = Qb + (long)(qw0 + fi * 16 + r) * 2304;
        qf[fi][0] = *(const short8*)(qrow + 8 * g);
        qf[fi][1] = *(const short8*)(qrow + 32 + 8 * g);
    }
    f32x4 oacc[2][4] = {};
    float mrow[2][4], lrow[2][4];
    #pragma unroll
    for (int fi = 0; fi < 2; ++fi)
        #pragma unroll
        for (int i = 0; i < 4; i++) { mrow[fi][i] = -1e30f; lrow[fi][i] = 0.f; }
    const float SC = 0.125f * 1.44269504f;

    auto stage = [&](int kt) {
        int kv0 = kvbase + kt * 64;
        u16* kb = Ks + (kt & 1) * 4096;
        u16* vb = Vs + (kt & 1) * 4096;
        #pragma unroll
        for (int j = 0; j < 2; ++j) {
            int cc = w * 128 + j * 64 + lane;
            int row = cc >> 3;
            int slot = (cc & 7) ^ (row & 7);
            gload_lds16(Kb + (long)(kv0 + row) * 2304 + slot * 8, kb + (w * 128 + j * 64) * 8);
            gload_lds16(Vtb + (long)row * 2048 + kv0 + slot * 8, vb + (w * 128 + j * 64) * 8);
        }
    };

    stage(0);
    for (int kt = 0; kt < nit; ++kt) {
        int kv0 = kvbase + kt * 64;
        if (kt + 1 < nit) {
            stage(kt + 1);
            asm volatile("s_waitcnt vmcnt(4)" ::: "memory");
        } else {
            asm volatile("s_waitcnt vmcnt(0)" ::: "memory");
        }
        __builtin_amdgcn_sched_barrier(0);
        __builtin_amdgcn_s_barrier();
        const u16* kb = Ks + (kt & 1) * 4096;
        const u16* vb = Vs + (kt & 1) * 4096;

        f32x4 sc[2][4] = {};
        float tmax[2][4];
        bool act[2];
        #pragma unroll
        for (int fi = 0; fi < 2; ++fi) {
            act[fi] = kv0 <= qw0 + fi * 16 + 15;
            if (!act[fi]) continue;
            #pragma unroll
            for (int nt = 0; nt < 4; ++nt) {
                #pragma unroll
                for (int kh = 0; kh < 2; ++kh) {
                    short8 bk = *(const short8*)(kb + (nt * 16 + r) * 64 + ((kh * 32 + g * 8) ^ ((r & 7) << 3)));
                    sc[fi][nt] = __builtin_amdgcn_mfma_f32_16x16x32_bf16(qf[fi][kh], bk, sc[fi][nt], 0, 0, 0);
                }
            }
            bool needmask = (kv0 + 63) > (qw0 + fi * 16);
            #pragma unroll
            for (int reg = 0; reg < 4; ++reg) tmax[fi][reg] = -1e30f;
            #pragma unroll
            for (int nt = 0; nt < 4; ++nt)
                #pragma unroll
                for (int reg = 0; reg < 4; ++reg) {
                    float sv = sc[fi][nt][reg] * SC;
                    if (needmask && (kv0 + nt * 16 + r) > (qw0 + fi * 16 + g * 4 + reg)) sv = -1e30f;
                    sc[fi][nt][reg] = sv;
                    tmax[fi][reg] = fmaxf(tmax[fi][reg], sv);
                }
            #pragma unroll
            for (int off = 1; off < 16; off <<= 1)
                #pragma unroll
                for (int reg = 0; reg < 4; ++reg)
                    tmax[fi][reg] = fmaxf(tmax[fi][reg], __shfl_xor(tmax[fi][reg], off));
        }

        bool need = false;
        #pragma unroll
        for (int fi = 0; fi < 2; ++fi)
            if (act[fi])
                #pragma unroll
                for (int reg = 0; reg < 4; ++reg)
                    need = need || (tmax[fi][reg] > mrow[fi][reg] + 8.f);
        if (__any(need)) {
            #pragma unroll
            for (int fi = 0; fi < 2; ++fi) {
                if (!act[fi]) continue;
                #pragma unroll
                for (int reg = 0; reg < 4; ++reg) {
                    float mnew = fmaxf(mrow[fi][reg], tmax[fi][reg]);
                    float alpha = exp2f(mrow[fi][reg] - mnew);
                    mrow[fi][reg] = mnew;
                    lrow[fi][reg] *= alpha;
                    #pragma unroll
                    for (int dt = 0; dt < 4; ++dt) oacc[fi][dt][reg] *= alpha;
                }
            }
        }

        #pragma unroll
        for (int fi = 0; fi < 2; ++fi) {
            if (!act[fi]) continue;
            float psum[4] = {0.f, 0.f, 0.f, 0.f};
            u16* Pw = Ps + (w * 32 + fi * 16) * 64;
            #pragma unroll
            for (int nt = 0; nt < 4; ++nt)
                #pragma unroll
                for (int reg = 0; reg < 4; ++reg) {
                    float p = exp2f(sc[fi][nt][reg] - mrow[fi][reg]);
                    psum[reg] += p;
                    int row = g * 4 + reg;
                    Pw[row * 64 + ((nt * 16 + r) ^ ((row & 7) << 3))] = f2bf(p);
                }
            #pragma unroll
            for (int off = 1; off < 16; off <<= 1)
                #pragma unroll
                for (int reg = 0; reg < 4; ++reg)
                    psum[reg] += __shfl_xor(psum[reg], off);
            #pragma unroll
            for (int reg = 0; reg < 4; ++reg)
                lrow[fi][reg] += psum[reg];

            short8 pf[2];
            pf[0] = *(const short8*)(Pw + r * 64 + ((g * 8) ^ ((r & 7) << 3)));
            pf[1] = *(const short8*)(Pw + r * 64 + ((32 + g * 8) ^ ((r & 7) << 3)));
            #pragma unroll
            for (int dt = 0; dt < 4; ++dt)
                #pragma unroll
                for (int kc = 0; kc < 2; ++kc) {
                    short8 vf = *(const short8*)(vb + (dt * 16 + r) * 64 + ((kc * 32 + g * 8) ^ ((r & 7) << 3)));
                    oacc[fi][dt] = __builtin_amdgcn_mfma_f32_16x16x32_bf16(pf[kc], vf, oacc[fi][dt], 0, 0, 0);
                }
        }
        __builtin_amdgcn_s_barrier();
    }

    long pbase = ((long)c * 24 + bh) * 2048;
    #pragma unroll
    for (int fi = 0; fi < 2; ++fi)
        #pragma unroll
        for (int dt = 0; dt < 4; ++dt)
            #pragma unroll
            for (int reg = 0; reg < 4; ++reg) {
                int q = qw0 + fi * 16 + g * 4 + reg;
                int d = dt * 16 + r;
                Opart[(pbase + q) * 64 + d] = f2bf(oacc[fi][dt][reg]);
            }
    if (r == 0) {
        #pragma unroll
        for (int fi = 0; fi < 2; ++fi)
            #pragma unroll
            for (int reg = 0; reg < 4; ++reg) {
                int q = qw0 + fi * 16 + g * 4 + reg;
                Ml[(pbase + q) * 2]     = mrow[fi][reg];
                Ml[(pbase + q) * 2 + 1] = lrow[fi][reg];
            }
    }
}

// ---------------- combine split-K partials -> Ob bf16 [B*S][768] ----------------
__global__ __launch_bounds__(256) void attn_combine(const u16* __restrict__ Opart,
                                                    const float* __restrict__ Ml,
                                                    u16* __restrict__ Ob) {
    int bh = blockIdx.y;
    int b = bh / 12, h = bh % 12;
    int q = blockIdx.x * 4 + (threadIdx.x >> 6);
    int d = threadIdx.x & 63;
    int qi = q >> 7;
    int nact = (qi >> 2) + 1;
    float mv[4], lv[4];
    float M = -1e30f;
    for (int c = 0; c < nact; ++c) {
        long base = ((long)c * 24 + bh) * 2048 + q;
        mv[c] = Ml[base * 2];
        lv[c] = Ml[base * 2 + 1];
        M = fmaxf(M, mv[c]);
    }
    float denom = 0.f, val = 0.f;
    for (int c = 0; c < nact; ++c) {
        float wgt = exp2f(mv[c] - M);
        denom += lv[c] * wgt;
        val += wgt * bf2f(Opart[(((long)c * 24 + bh) * 2048 + q) * 64 + d]);
    }
    Ob[((long)b * 2048 + q) * 768 + h * 64 + d] = f2bf(val / denom);
}

extern "C" void kernel_launch(void* const* d_in, const int* in_sizes, int n_in,
                              void* d_out, int out_size, void* d_ws, size_t ws_size,
                              hipStream_t stream) {
    const float* x     = (const float*)d_in[0];
    const float* ln1_g = (const float*)d_in[1];
    const float* ln1_b = (const float*)d_in[2];
    const float* ln2_g = (const float*)d_in[3];
    const float* ln2_b = (const float*)d_in[4];
    const float* w_qkv = (const float*)d_in[5];
    const float* b_qkv = (const float*)d_in[6];
    const float* w_out = (const float*)d_in[7];
    const float* b_out = (const float*)d_in[8];
    const float* w_fc1 = (const float*)d_in[9];
    const float* b_fc1 = (const float*)d_in[10];
    const float* w_fc2 = (const float*)d_in[11];
    const float* b_fc2 = (const float*)d_in[12];

    char* ws = (char*)d_ws;
    size_t off = 0;
    auto alloc = [&](size_t bytes) { void* p = ws + off; off += (bytes + 255) & ~255ULL; return p; };
    u16* h1    = (u16*)alloc(4096UL * 768 * 2);    // dead after qkv GEMM
    u16* WqkvT = (u16*)alloc(2304UL * 768 * 2);    // dead after qkv GEMM
    u16* WoutT = (u16*)alloc(768UL * 768 * 2);     // dead after out-proj
    u16* Wfc1T = (u16*)alloc(3072UL * 768 * 2);    // dead after fc1
    u16* Wfc2T = (u16*)alloc(768UL * 3072 * 2);
    u16* qkvb  = (u16*)alloc(4096UL * 2304 * 2);   // dead after attn
    u16* Vtb   = (u16*)alloc(24UL * 64 * 2048 * 2);
    u16* Ob    = (u16*)alloc(4096UL * 768 * 2);
    float* x2  = (float*)alloc(4096UL * 768 * 4);
    // pool shared (time-disjoint): [h2 | gbuf] vs [Opart | Ml]
    char* pool = (char*)alloc(4096UL * 768 * 2 + 4096UL * 3072 * 2);
    u16* h2      = (u16*)pool;
    u16* gbuf    = (u16*)(pool + 4096UL * 768 * 2);
    u16* Opart   = (u16*)pool;
    float* Ml    = (float*)(pool + 4UL * 24 * 2048 * 64 * 2);
    // fc2 split-K fp32 partials, aliased over buffers dead by fc2 time:
    float* P0 = (float*)qkvb;   // 12.6MB <= 18.9MB
    float* P1 = (float*)h1;     // 12.6MB <= h1..Wfc1T contiguous 15.7MB

    transpose_w<<<dim3(2304 / 32, 768 / 32), 256, 0, stream>>>(w_qkv, WqkvT, 768, 2304);
    transpose_w<<<dim3(768 / 32, 768 / 32), 256, 0, stream>>>(w_out, WoutT, 768, 768);
    transpose_w<<<dim3(3072 / 32, 768 / 32), 256, 0, stream>>>(w_fc1, Wfc1T, 768, 3072);
    transpose_w<<<dim3(768 / 32, 3072 / 32), 256, 0, stream>>>(w_fc2, Wfc2T, 3072, 768);

    ln_kernel<<<4096, 256, 0, stream>>>(x, ln1_g, ln1_b, h1);
    gemm_bf16<0><<<dim3(18, 32, 1), 256, 0, stream>>>(h1, 768, WqkvT, 768, b_qkv, nullptr, qkvb, nullptr, 4096, 2304, 768);
    transpose_v<<<dim3(32, 24), 256, 0, stream>>>(qkvb, Vtb);
    attn_kernel<<<dim3(960), 256, 0, stream>>>(qkvb, Vtb, Opart, Ml);
    attn_combine<<<dim3(512, 24), 256, 0, stream>>>(Opart, Ml, Ob);
    gemm_bf16<1><<<dim3(6, 32, 1), 256, 0, stream>>>(Ob, 768, WoutT, 768, b_out, x, x2, nullptr, 4096, 768, 768);
    ln_kernel<<<4096, 256, 0, stream>>>(x2, ln2_g, ln2_b, h2);
    gemm_bf16<2><<<dim3(24, 32, 1), 256, 0, stream>>>(h2, 768, Wfc1T, 768, b_fc1, nullptr, gbuf, nullptr, 4096, 3072, 768);
    gemm_bf16<3><<<dim3(6, 32, 2), 256, 0, stream>>>(gbuf, 3072, Wfc2T, 3072, nullptr, nullptr, P0, P1, 4096, 768, 1536);
    fc2_combine<<<4096, 192, 0, stream>>>(P0, P1, b_fc2, x2, (float*)d_out);
}

// Round 6
// 225.634 us; speedup vs baseline: 1.7116x; 1.0751x over previous
//
#include <hip/hip_runtime.h>
#include <hip/hip_bf16.h>

typedef unsigned short u16;
typedef unsigned int u32;
typedef unsigned char u8;
using short8 = __attribute__((ext_vector_type(8))) short;
using f32x4  = __attribute__((ext_vector_type(4))) float;
using float4v = __attribute__((ext_vector_type(4))) float;

__device__ __forceinline__ u16 f2bf(float f) {
    __hip_bfloat16 h = __float2bfloat16(f);
    union { __hip_bfloat16 h; u16 u; } cv; cv.h = h; return cv.u;
}
__device__ __forceinline__ float bf2f(u16 u) {
    union { u32 u; float f; } cv; cv.u = ((u32)u) << 16; return cv.f;
}
__device__ __forceinline__ u16 f2bf_trunc(float f) {
    union { float f; u32 u; } cv; cv.f = f; return (u16)(cv.u >> 16);
}

__device__ __forceinline__ void gload_lds16(const void* g, void* l) {
    __builtin_amdgcn_global_load_lds(
        (const __attribute__((address_space(1))) u32*)g,
        (__attribute__((address_space(3))) u32*)l, 16, 0, 0);
}

// ---------------- transpose + fp32->bf16 convert: W[K][N] -> Wt[N][K] ----------------
__global__ __launch_bounds__(256) void transpose_w(const float* __restrict__ W,
                                                   u16* __restrict__ Wt, int K, int N) {
    __shared__ float tile[32][33];
    int n0 = blockIdx.x * 32, k0 = blockIdx.y * 32;
    int tx = threadIdx.x & 31, ty = threadIdx.x >> 5;
    for (int i = 0; i < 4; i++) {
        int k = ty + i * 8;
        tile[k][tx] = W[(long)(k0 + k) * N + n0 + tx];
    }
    __syncthreads();
    for (int i = 0; i < 4; i++) {
        int n = ty + i * 8;
        Wt[(long)(n0 + n) * K + k0 + tx] = f2bf(tile[tx][n]);
    }
}

// ---------------- V transpose: qkv[B][S][2304] (V slice) -> Vt[B*H][64][2048] ------------
__global__ __launch_bounds__(256) void transpose_v(const u16* __restrict__ qkv,
                                                   u16* __restrict__ Vt) {
    __shared__ u16 tile[64][72];
    int s0 = blockIdx.x * 64;
    int bh = blockIdx.y;
    int b = bh / 12, h = bh % 12;
    int tid = threadIdx.x;
    const u16* src = qkv + (long)b * 2048 * 2304 + 1536 + h * 64;
    #pragma unroll
    for (int j = 0; j < 2; ++j) {
        int c = tid + j * 256;
        int srow = c >> 3, ch = c & 7;
        *(short8*)&tile[srow][ch * 8] = *(const short8*)(src + (long)(s0 + srow) * 2304 + ch * 8);
    }
    __syncthreads();
    u16* dst = Vt + (long)bh * 64 * 2048 + s0;
    #pragma unroll
    for (int j = 0; j < 2; ++j) {
        int c = tid + j * 256;
        int d = c >> 3, ch = c & 7;
        short8 v;
        #pragma unroll
        for (int e = 0; e < 8; ++e) v[e] = (short)tile[ch * 8 + e][d];
        *(short8*)(dst + (long)d * 2048 + ch * 8) = v;
    }
}

// ---------------- LayerNorm fp32 -> bf16 ----------------
__global__ __launch_bounds__(256) void ln_kernel(const float* __restrict__ x,
                                                 const float* __restrict__ gain,
                                                 const float* __restrict__ beta,
                                                 u16* __restrict__ out) {
    int row = blockIdx.x;
    const float* xr = x + (long)row * 768;
    int tid = threadIdx.x;
    float v[3];
    float s = 0.f, s2 = 0.f;
    for (int j = 0; j < 3; j++) {
        v[j] = xr[tid + 256 * j];
        s += v[j]; s2 += v[j] * v[j];
    }
    for (int off = 32; off; off >>= 1) {
        s  += __shfl_down(s, off);
        s2 += __shfl_down(s2, off);
    }
    __shared__ float ws[8];
    int lane = tid & 63, w = tid >> 6;
    if (lane == 0) { ws[w] = s; ws[4 + w] = s2; }
    __syncthreads();
    s  = ws[0] + ws[1] + ws[2] + ws[3];
    s2 = ws[4] + ws[5] + ws[6] + ws[7];
    float mu  = s * (1.f / 768.f);
    float var = s2 * (1.f / 768.f) - mu * mu;
    float rs  = rsqrtf(var + 1e-5f);
    for (int j = 0; j < 3; j++) {
        int c = tid + 256 * j;
        out[(long)row * 768 + c] = f2bf((v[j] - mu) * rs * gain[c] + beta[c]);
    }
}

// ---------------- bf16 GEMM v2: 128x128 tile, BK=64, double-buffered counted-vmcnt ------
template <int EPI>
__global__ __launch_bounds__(256) void gemm_bf16(const u16* __restrict__ A, int lda,
                                                 const u16* __restrict__ Bt, int ldb,
                                                 const float* __restrict__ bias,
                                                 const float* __restrict__ res,
                                                 void* __restrict__ Cout0,
                                                 void* __restrict__ Cout1,
                                                 int M, int N, int K) {
    __shared__ alignas(16) u16 As[2][128 * 64];
    __shared__ alignas(16) u16 Bs[2][128 * 64];
    int tN = blockIdx.x * 128, tM = blockIdx.y * 128;
    int z = blockIdx.z;
    const u16* Ab = A + (long)z * K;
    const u16* Bb = Bt + (long)z * K;
    void* Cw = z ? Cout1 : Cout0;
    int tid = threadIdx.x;
    int wid = tid >> 6, lane = tid & 63;
    int wm = wid >> 1, wn = wid & 1;
    int g = lane >> 4, r = lane & 15;
    int row0 = tid >> 3, ch = tid & 7;

    f32x4 acc[4][4] = {};
    int KT = K >> 6;

    auto stage = [&](int kt) {
        int k0 = kt << 6;
        u16* ab = As[kt & 1];
        u16* bb = Bs[kt & 1];
        #pragma unroll
        for (int p = 0; p < 4; ++p) {
            int row = p * 32 + row0;
            int slot = ch ^ (row & 7);
            gload_lds16(Ab + (long)(tM + row) * lda + k0 + slot * 8, ab + (p * 256 + wid * 64) * 8);
        }
        #pragma unroll
        for (int p = 0; p < 4; ++p) {
            int row = p * 32 + row0;
            int slot = ch ^ (row & 7);
            gload_lds16(Bb + (long)(tN + row) * ldb + k0 + slot * 8, bb + (p * 256 + wid * 64) * 8);
        }
    };

    stage(0);
    for (int kt = 0; kt < KT; ++kt) {
        if (kt + 1 < KT) {
            stage(kt + 1);
            asm volatile("s_waitcnt vmcnt(8)" ::: "memory");
        } else {
            asm volatile("s_waitcnt vmcnt(0)" ::: "memory");
        }
        __builtin_amdgcn_sched_barrier(0);
        __builtin_amdgcn_s_barrier();
        const u16* ab = As[kt & 1];
        const u16* bb = Bs[kt & 1];

        short8 af[2][4], bf[2][4];
        #pragma unroll
        for (int kh = 0; kh < 2; ++kh)
            #pragma unroll
            for (int mi = 0; mi < 4; ++mi) {
                int row = wm * 64 + mi * 16 + r;
                af[kh][mi] = *(const short8*)(ab + row * 64 + (((kh * 4 + g) ^ (row & 7)) * 8));
            }
        #pragma unroll
        for (int kh = 0; kh < 2; ++kh)
            #pragma unroll
            for (int ni = 0; ni < 4; ++ni) {
                int row = wn * 64 + ni * 16 + r;
                bf[kh][ni] = *(const short8*)(bb + row * 64 + (((kh * 4 + g) ^ (row & 7)) * 8));
            }
        #pragma unroll
        for (int kh = 0; kh < 2; ++kh)
            #pragma unroll
            for (int mi = 0; mi < 4; ++mi)
                #pragma unroll
                for (int ni = 0; ni < 4; ++ni)
                    acc[mi][ni] = __builtin_amdgcn_mfma_f32_16x16x32_bf16(af[kh][mi], bf[kh][ni], acc[mi][ni], 0, 0, 0);
        __builtin_amdgcn_s_barrier();
    }

    #pragma unroll
    for (int mi = 0; mi < 4; mi++) {
        #pragma unroll
        for (int ni = 0; ni < 4; ni++) {
            int col = tN + wn * 64 + ni * 16 + r;
            float bv = (EPI == 3) ? 0.f : bias[col];
            #pragma unroll
            for (int reg = 0; reg < 4; reg++) {
                int row = tM + wm * 64 + mi * 16 + g * 4 + reg;
                float v = acc[mi][ni][reg] + bv;
                if (EPI == 1) {
                    v += res[(long)row * N + col];
                    ((float*)Cw)[(long)row * N + col] = v;
                } else if (EPI == 2) {
                    v = 0.5f * v * (1.f + erff(v * 0.70710678118f));
                    ((u16*)Cw)[(long)row * N + col] = f2bf(v);
                } else if (EPI == 3) {
                    ((float*)Cw)[(long)row * N + col] = v;
                } else {
                    ((u16*)Cw)[(long)row * N + col] = f2bf(v);
                }
            }
        }
    }
}

// ---------------- fc2 split-K combine: out = P0 + P1 + bias + res (fp32) ----------------
__global__ __launch_bounds__(192) void fc2_combine(const float* __restrict__ P0,
                                                   const float* __restrict__ P1,
                                                   const float* __restrict__ bias,
                                                   const float* __restrict__ res,
                                                   float* __restrict__ out) {
    long row = blockIdx.x;
    int c = threadIdx.x * 4;
    long i = row * 768 + c;
    float4v a = *(const float4v*)(P0 + i);
    float4v b = *(const float4v*)(P1 + i);
    float4v bs = *(const float4v*)(bias + c);
    float4v rr = *(const float4v*)(res + i);
    float4v o = a + b + bs + rr;
    *(float4v*)(out + i) = o;
}

// ---------------- split-K flash attention (causal), VALU-diet version ----------------
// mrow starts at 8 (defer-max never fires for this data scale; general path kept).
// Per-lane psum partials reduced once at the end. P stored by truncation.
__device__ __constant__ u8 SLOT_QI[40] = {
    15,15,15,15, 14,14,14, 13,13,13, 12,12,12, 11,11,11, 10,10, 9,9, 8,8, 7,7, 6, 5, 4, 3,
    14,10,6,2,  13,9,5,1,  12,8,4,0 };
__device__ __constant__ u8 SLOT_C[40] = {
    0,1,2,3, 0,1,2, 0,1,2, 0,1,2, 0,1,2, 0,1, 0,1, 0,1, 0,1, 0, 0, 0, 0,
    3,2,1,0, 3,2,1,0, 3,2,1,0 };

__global__ __launch_bounds__(256) void attn_kernel(const u16* __restrict__ qkv,
                                                   const u16* __restrict__ Vt,
                                                   u16* __restrict__ Opart,
                                                   float* __restrict__ Ml) {
    __shared__ alignas(16) u16 Ks[2 * 64 * 64];
    __shared__ alignas(16) u16 Vs[2 * 64 * 64];
    __shared__ alignas(16) u16 Ps[4 * 32 * 64];
    int flat = blockIdx.x;
    int s = flat / 24, bh = flat % 24;
    int qi = SLOT_QI[s], c = SLOT_C[s];
    int b = bh / 12, h = bh % 12;
    int tid = threadIdx.x;
    int w = tid >> 6, lane = tid & 63;
    int g = lane >> 4, r = lane & 15;
    int qt0 = qi * 128;
    int qw0 = qt0 + w * 32;
    int kvbase = c * 512;
    int nit = (c < (qi >> 2)) ? 8 : (2 * (qi & 3) + 2);
    const u16* base = qkv + (long)b * 2048 * 2304;
    const u16* Qb = base + h * 64;
    const u16* Kb = base + 768 + h * 64;
    const u16* Vtb = Vt + (long)bh * 64 * 2048;

    const float SC = 0.125f * 1.44269504f;   // fold scale*log2(e) into Q
    short8 qf[2][2];
    #pragma unroll
    for (int fi = 0; fi < 2; ++fi) {
        const u16* qrow = Qb + (long)(qw0 + fi * 16 + r) * 2304;
        qf[fi][0] = *(const short8*)(qrow + 8 * g);
        qf[fi][1] = *(const short8*)(qrow + 32 + 8 * g);
        #pragma unroll
        for (int kh = 0; kh < 2; ++kh)
            #pragma unroll
            for (int j = 0; j < 8; ++j)
                qf[fi][kh][j] = (short)f2bf(bf2f((u16)qf[fi][kh][j]) * SC);
    }

    f32x4 oacc[2][4] = {};
    float mrow[2][4], psum[2][4];
    #pragma unroll
    for (int fi = 0; fi < 2; ++fi)
        #pragma unroll
        for (int i = 0; i < 4; i++) { mrow[fi][i] = 8.0f; psum[fi][i] = 0.f; }

    auto stage = [&](int kt) {
        int kv0 = kvbase + kt * 64;
        u16* kb = Ks + (kt & 1) * 4096;
        u16* vb = Vs + (kt & 1) * 4096;
        #pragma unroll
        for (int j = 0; j < 2; ++j) {
            int cc = w * 128 + j * 64 + lane;
            int row = cc >> 3;
            int slot = (cc & 7) ^ (row & 7);
            gload_lds16(Kb + (long)(kv0 + row) * 2304 + slot * 8, kb + (w * 128 + j * 64) * 8);
            gload_lds16(Vtb + (long)row * 2048 + kv0 + slot * 8, vb + (w * 128 + j * 64) * 8);
        }
    };

    stage(0);
    for (int kt = 0; kt < nit; ++kt) {
        int kv0 = kvbase + kt * 64;
        if (kt + 1 < nit) {
            stage(kt + 1);
            asm volatile("s_waitcnt vmcnt(4)" ::: "memory");
        } else {
            asm volatile("s_waitcnt vmcnt(0)" ::: "memory");
        }
        __builtin_amdgcn_sched_barrier(0);
        __builtin_amdgcn_s_barrier();
        const u16* kb = Ks + (kt & 1) * 4096;
        const u16* vb = Vs + (kt & 1) * 4096;

        bool act0 = kv0 <= qw0 + 15;
        bool act1 = kv0 <= qw0 + 31;

        f32x4 sc[2][4] = {};
        if (act1) {
            // QK^T: shared K fragment feeds both row-fragments
            #pragma unroll
            for (int nt = 0; nt < 4; ++nt)
                #pragma unroll
                for (int kh = 0; kh < 2; ++kh) {
                    short8 bk = *(const short8*)(kb + (nt * 16 + r) * 64 + ((kh * 32 + g * 8) ^ ((r & 7) << 3)));
                    sc[1][nt] = __builtin_amdgcn_mfma_f32_16x16x32_bf16(qf[1][kh], bk, sc[1][nt], 0, 0, 0);
                    if (act0)
                        sc[0][nt] = __builtin_amdgcn_mfma_f32_16x16x32_bf16(qf[0][kh], bk, sc[0][nt], 0, 0, 0);
                }

            // causal mask, only on diagonal tiles (wave-uniform branch)
            #pragma unroll
            for (int fi = 0; fi < 2; ++fi) {
                if (fi == 0 && !act0) continue;
                if ((kv0 + 63) > (qw0 + fi * 16)) {
                    #pragma unroll
                    for (int nt = 0; nt < 4; ++nt)
                        #pragma unroll
                        for (int reg = 0; reg < 4; ++reg)
                            if ((kv0 + nt * 16 + r) > (qw0 + fi * 16 + g * 4 + reg))
                                sc[fi][nt][reg] = -1e30f;
                }
            }

            // defer-max trigger: per-lane partial max only (no cross-lane reduce)
            float tl[2][4];
            bool need = false;
            #pragma unroll
            for (int fi = 0; fi < 2; ++fi) {
                if (fi == 0 && !act0) continue;
                #pragma unroll
                for (int reg = 0; reg < 4; ++reg) {
                    tl[fi][reg] = fmaxf(fmaxf(sc[fi][0][reg], sc[fi][1][reg]),
                                        fmaxf(sc[fi][2][reg], sc[fi][3][reg]));
                    need = need || (tl[fi][reg] > mrow[fi][reg] + 8.f);
                }
            }
            if (__any(need)) {   // rare path: exact row max + rescale
                #pragma unroll
                for (int fi = 0; fi < 2; ++fi) {
                    if (fi == 0 && !act0) continue;
                    #pragma unroll
                    for (int reg = 0; reg < 4; ++reg) {
                        float rm = tl[fi][reg];
                        #pragma unroll
                        for (int off = 1; off < 16; off <<= 1)
                            rm = fmaxf(rm, __shfl_xor(rm, off));
                        float mnew = fmaxf(mrow[fi][reg], rm);
                        float alpha = exp2f(mrow[fi][reg] - mnew);
                        mrow[fi][reg] = mnew;
                        psum[fi][reg] *= alpha;
                        #pragma unroll
                        for (int dt = 0; dt < 4; ++dt) oacc[fi][dt][reg] *= alpha;
                    }
                }
            }

            // P = exp2(sc - m): accumulate per-lane psum, truncate-store to LDS
            #pragma unroll
            for (int fi = 0; fi < 2; ++fi) {
                if (fi == 0 && !act0) continue;
                u16* Pw = Ps + (w * 32 + fi * 16) * 64;
                #pragma unroll
                for (int nt = 0; nt < 4; ++nt)
                    #pragma unroll
                    for (int reg = 0; reg < 4; ++reg) {
                        float p = exp2f(sc[fi][nt][reg] - mrow[fi][reg]);
                        psum[fi][reg] += p;
                        int row = g * 4 + reg;
                        Pw[row * 64 + ((nt * 16 + r) ^ ((row & 7) << 3))] = f2bf_trunc(p);
                    }
            }

            // PV: shared V fragment feeds both row-fragments
            short8 pf[2][2];
            #pragma unroll
            for (int fi = 0; fi < 2; ++fi) {
                if (fi == 0 && !act0) continue;
                const u16* Pw = Ps + (w * 32 + fi * 16) * 64;
                pf[fi][0] = *(const short8*)(Pw + r * 64 + ((g * 8) ^ ((r & 7) << 3)));
                pf[fi][1] = *(const short8*)(Pw + r * 64 + ((32 + g * 8) ^ ((r & 7) << 3)));
            }
            #pragma unroll
            for (int dt = 0; dt < 4; ++dt)
                #pragma unroll
                for (int kc = 0; kc < 2; ++kc) {
                    short8 vf = *(const short8*)(vb + (dt * 16 + r) * 64 + ((kc * 32 + g * 8) ^ ((r & 7) << 3)));
                    oacc[1][dt] = __builtin_amdgcn_mfma_f32_16x16x32_bf16(pf[1][kc], vf, oacc[1][dt], 0, 0, 0);
                    if (act0)
                        oacc[0][dt] = __builtin_amdgcn_mfma_f32_16x16x32_bf16(pf[0][kc], vf, oacc[0][dt], 0, 0, 0);
                }
        }
        __builtin_amdgcn_s_barrier();
    }

    // one-time cross-lane reduction of psum partials
    float lrow[2][4];
    #pragma unroll
    for (int fi = 0; fi < 2; ++fi)
        #pragma unroll
        for (int reg = 0; reg < 4; ++reg) {
            float l = psum[fi][reg];
            #pragma unroll
            for (int off = 1; off < 16; off <<= 1)
                l += __shfl_xor(l, off);
            lrow[fi][reg] = l;
        }

    long pbase = ((long)c * 24 + bh) * 2048;
    #pragma unroll
    for (int fi = 0; fi < 2; ++fi)
        #pragma unroll
        for (int dt = 0; dt < 4; ++dt)
            #pragma unroll
            for (int reg = 0; reg < 4; ++reg) {
                int q = qw0 + fi * 16 + g * 4 + reg;
                int d = dt * 16 + r;
                Opart[(pbase + q) * 64 + d] = f2bf(oacc[fi][dt][reg]);
            }
    if (r == 0) {
        #pragma unroll
        for (int fi = 0; fi < 2; ++fi)
            #pragma unroll
            for (int reg = 0; reg < 4; ++reg) {
                int q = qw0 + fi * 16 + g * 4 + reg;
                Ml[(pbase + q) * 2]     = mrow[fi][reg];
                Ml[(pbase + q) * 2 + 1] = lrow[fi][reg];
            }
    }
}

// ---------------- combine split-K partials -> Ob bf16 [B*S][768] ----------------
__global__ __launch_bounds__(256) void attn_combine(const u16* __restrict__ Opart,
                                                    const float* __restrict__ Ml,
                                                    u16* __restrict__ Ob) {
    int bh = blockIdx.y;
    int b = bh / 12, h = bh % 12;
    int q = blockIdx.x * 4 + (threadIdx.x >> 6);
    int d = threadIdx.x & 63;
    int qi = q >> 7;
    int nact = (qi >> 2) + 1;
    float mv[4], lv[4];
    float M = -1e30f;
    for (int c = 0; c < nact; ++c) {
        long base = ((long)c * 24 + bh) * 2048 + q;
        mv[c] = Ml[base * 2];
        lv[c] = Ml[base * 2 + 1];
        M = fmaxf(M, mv[c]);
    }
    float denom = 0.f, val = 0.f;
    for (int c = 0; c < nact; ++c) {
        float wgt = exp2f(mv[c] - M);
        denom += lv[c] * wgt;
        val += wgt * bf2f(Opart[(((long)c * 24 + bh) * 2048 + q) * 64 + d]);
    }
    Ob[((long)b * 2048 + q) * 768 + h * 64 + d] = f2bf(val / denom);
}

extern "C" void kernel_launch(void* const* d_in, const int* in_sizes, int n_in,
                              void* d_out, int out_size, void* d_ws, size_t ws_size,
                              hipStream_t stream) {
    const float* x     = (const float*)d_in[0];
    const float* ln1_g = (const float*)d_in[1];
    const float* ln1_b = (const float*)d_in[2];
    const float* ln2_g = (const float*)d_in[3];
    const float* ln2_b = (const float*)d_in[4];
    const float* w_qkv = (const float*)d_in[5];
    const float* b_qkv = (const float*)d_in[6];
    const float* w_out = (const float*)d_in[7];
    const float* b_out = (const float*)d_in[8];
    const float* w_fc1 = (const float*)d_in[9];
    const float* b_fc1 = (const float*)d_in[10];
    const float* w_fc2 = (const float*)d_in[11];
    const float* b_fc2 = (const float*)d_in[12];

    char* ws = (char*)d_ws;
    size_t off = 0;
    auto alloc = [&](size_t bytes) { void* p = ws + off; off += (bytes + 255) & ~255ULL; return p; };
    u16* h1    = (u16*)alloc(4096UL * 768 * 2);    // dead after qkv GEMM
    u16* WqkvT = (u16*)alloc(2304UL * 768 * 2);    // dead after qkv GEMM
    u16* WoutT = (u16*)alloc(768UL * 768 * 2);     // dead after out-proj
    u16* Wfc1T = (u16*)alloc(3072UL * 768 * 2);    // dead after fc1
    u16* Wfc2T = (u16*)alloc(768UL * 3072 * 2);
    u16* qkvb  = (u16*)alloc(4096UL * 2304 * 2);   // dead after attn
    u16* Vtb   = (u16*)alloc(24UL * 64 * 2048 * 2);
    u16* Ob    = (u16*)alloc(4096UL * 768 * 2);
    float* x2  = (float*)alloc(4096UL * 768 * 4);
    // pool shared (time-disjoint): [h2 | gbuf] vs [Opart | Ml]
    char* pool = (char*)alloc(4096UL * 768 * 2 + 4096UL * 3072 * 2);
    u16* h2      = (u16*)pool;
    u16* gbuf    = (u16*)(pool + 4096UL * 768 * 2);
    u16* Opart   = (u16*)pool;
    float* Ml    = (float*)(pool + 4UL * 24 * 2048 * 64 * 2);
    // fc2 split-K fp32 partials, aliased over buffers dead by fc2 time:
    float* P0 = (float*)qkvb;
    float* P1 = (float*)h1;

    transpose_w<<<dim3(2304 / 32, 768 / 32), 256, 0, stream>>>(w_qkv, WqkvT, 768, 2304);
    transpose_w<<<dim3(768 / 32, 768 / 32), 256, 0, stream>>>(w_out, WoutT, 768, 768);
    transpose_w<<<dim3(3072 / 32, 768 / 32), 256, 0, stream>>>(w_fc1, Wfc1T, 768, 3072);
    transpose_w<<<dim3(768 / 32, 3072 / 32), 256, 0, stream>>>(w_fc2, Wfc2T, 3072, 768);

    ln_kernel<<<4096, 256, 0, stream>>>(x, ln1_g, ln1_b, h1);
    gemm_bf16<0><<<dim3(18, 32, 1), 256, 0, stream>>>(h1, 768, WqkvT, 768, b_qkv, nullptr, qkvb, nullptr, 4096, 2304, 768);
    transpose_v<<<dim3(32, 24), 256, 0, stream>>>(qkvb, Vtb);
    attn_kernel<<<dim3(960), 256, 0, stream>>>(qkvb, Vtb, Opart, Ml);
    attn_combine<<<dim3(512, 24), 256, 0, stream>>>(Opart, Ml, Ob);
    gemm_bf16<1><<<dim3(6, 32, 1), 256, 0, stream>>>(Ob, 768, WoutT, 768, b_out, x, x2, nullptr, 4096, 768, 768);
    ln_kernel<<<4096, 256, 0, stream>>>(x2, ln2_g, ln2_b, h2);
    gemm_bf16<2><<<dim3(24, 32, 1), 256, 0, stream>>>(h2, 768, Wfc1T, 768, b_fc1, nullptr, gbuf, nullptr, 4096, 3072, 768);
    gemm_bf16<3><<<dim3(6, 32, 2), 256, 0, stream>>>(gbuf, 3072, Wfc2T, 3072, nullptr, nullptr, P0, P1, 4096, 768, 1536);
    fc2_combine<<<4096, 192, 0, stream>>>(P0, P1, b_fc2, x2, (float*)d_out);
}